// Round 6
// baseline (709.369 us; speedup 1.0000x reference)
//
#include <hip/hip_runtime.h>
#include <math.h>

#define BATCH 256
#define NNODE 128
#define NT    32768      // BATCH*NNODE
#define FDIM  128
#define NEDGE 262144
#define LBL   29
#define MAXDEG 16
#define RWD   16
#define NTF   (NT * FDIM)
#define ESTRIDE 2048     // per-graph CSR slot (mean 1024, sigma 32 -> 32-sigma margin)

// ---------------------------------------------------------------- CSR build (side-fused)
__global__ void k_deg2(const int* __restrict__ dst1, const int* __restrict__ dst2,
                       int* __restrict__ d1, int* __restrict__ d2) {
  int e = blockIdx.x * 256 + threadIdx.x;
  if (e < NEDGE) atomicAdd(&d1[dst1[e]], 1);
  else if (e < 2 * NEDGE) atomicAdd(&d2[dst2[e - NEDGE]], 1);
}
// per-graph local scan + dinv: one block per (side, graph), fully parallel
// (replaces the 2-block global scan that left the GPU idle)
__global__ __launch_bounds__(128) void k_scanl(const int* __restrict__ degi1,
                                               int* __restrict__ ofs1, int* __restrict__ cur1,
                                               float* __restrict__ dinv1,
                                               const int* __restrict__ degi2,
                                               int* __restrict__ ofs2, int* __restrict__ cur2,
                                               float* __restrict__ dinv2) {
  const int side = blockIdx.x >> 8;
  const int g = blockIdx.x & 255;
  const int* degi = side ? degi2 : degi1;
  int* ofs   = side ? ofs2  : ofs1;
  int* cur   = side ? cur2  : cur1;
  float* dnv = side ? dinv2 : dinv1;
  const int t = threadIdx.x;
  const int node = g * NNODE + t;
  int dg = degi[node];
  dnv[node] = rsqrtf((float)(dg + 1));   // +1 self loop
  // inclusive scan over 128 threads (2 waves)
  int lane = t & 63, wv = t >> 6;
  int v = dg;
  for (int off = 1; off < 64; off <<= 1) {
    int u = __shfl_up(v, off);
    if (lane >= off) v += u;
  }
  __shared__ int wsum[2];
  if (lane == 63) wsum[wv] = v;
  __syncthreads();
  int excl = v - dg + (wv ? wsum[0] : 0);
  int base = g * ESTRIDE + excl;
  ofs[node] = base;
  cur[node] = base;
}
__global__ void k_fill2(const int* __restrict__ src1, const int* __restrict__ dst1,
                        int* __restrict__ cur1, int* __restrict__ csr1,
                        const int* __restrict__ src2, const int* __restrict__ dst2,
                        int* __restrict__ cur2, int* __restrict__ csr2) {
  int e = blockIdx.x * 256 + threadIdx.x;
  if (e < NEDGE) {
    int pos = atomicAdd(&cur1[dst1[e]], 1);
    csr1[pos] = src1[e];
  } else if (e < 2 * NEDGE) {
    e -= NEDGE;
    int pos = atomicAdd(&cur2[dst2[e]], 1);
    csr2[pos] = src2[e];
  }
}

// ---------------------------------------------------------------- fused per-graph chain
// One block = one (graph, side). 256 threads, 78336 B LDS -> 2 blocks/CU.
// THIS ROUND: conv-layer mm reads W directly from global (L2-resident,
// 8-lane-shared imm-offset loads) -> the 16 staging barriers per layer (48
// per block) are GONE and the un-barriered k-loop software-pipelines.
// Unlike R3's failed prefetch, no register live-ranges cross barriers.
// Phase 0 (ragged 61-row initW) keeps the proven WcB staging.
__global__ __launch_bounds__(256, 2) void k_chain(
    const float* __restrict__ x1, const int* __restrict__ cent1, const float* __restrict__ rw1,
    const float* __restrict__ x2, const int* __restrict__ cent2, const float* __restrict__ rw2,
    const float* __restrict__ demb,
    const float* __restrict__ initW, const float* __restrict__ initb,
    const float* __restrict__ W1, const float* __restrict__ b1,
    const float* __restrict__ W2, const float* __restrict__ b2,
    const float* __restrict__ W3, const float* __restrict__ b3,
    const int* __restrict__ ofs1, const int* __restrict__ end1, const int* __restrict__ csr1,
    const int* __restrict__ ofs2, const int* __restrict__ end2, const int* __restrict__ csr2,
    const float* __restrict__ dinv1, const float* __restrict__ dinv2,
    float* __restrict__ feat1G, float* __restrict__ feat2G,
    float* __restrict__ f13G, float* __restrict__ f23G,
    float* __restrict__ gfs) {
  __shared__ float X[128 * 132];      // 67584 B: concat / feat / h (phase-shared)
  __shared__ float WcB[16 * 132];     // 8448 B: phase-0 W chunk / pool tmp [8*128]
  __shared__ float dvL[128];
  __shared__ float bL[128];
  __shared__ int   oL[128], enL[128];

  const int t = threadIdx.x;
  const int side = blockIdx.x >> 8;
  const int g = blockIdx.x & 255;
  const int nb = g * NNODE;

  const float* xg    = side ? x2 : x1;
  const int*   centg = side ? cent2 : cent1;
  const float* rwg   = side ? rw2 : rw1;
  const int*   ofsg  = side ? ofs2 : ofs1;
  const int*   endg  = side ? end2 : end1;
  const int*   csrg  = side ? csr2 : csr1;
  const float* dinvg = side ? dinv2 : dinv1;
  float* featG = side ? feat2G : feat1G;
  float* f3G   = side ? f23G : f13G;

  // -------- phase -1: stage dinv / csr offsets / concat features into X
  const int e_base = ofsg[nb];
  if (t < 128) {
    dvL[t] = dinvg[nb + t];
    oL[t]  = ofsg[nb + t] - e_base;
    enL[t] = endg[nb + t] - e_base;
  }
  {
    int d = t >> 1, sub = t & 1;          // 2 threads per node, 34 cols each
    int node = nb + d;
    int ct = centg[node];
    const float* xr = xg + (size_t)node * LBL;
    const float* er = demb + ct * MAXDEG;
    const float* rr = rwg + (size_t)node * RWD;
    for (int c = sub * 34; c < sub * 34 + 34; ++c) {
      float v = 0.f;
      if (c < LBL) v = xr[c];
      else if (c < LBL + MAXDEG) v = er[c - LBL];
      else if (c < 61) v = rr[c - 45];
      X[d * 68 + c] = v;                  // concat overlay, stride 68
    }
  }
  __syncthreads();

  const int rg = t >> 3;           // row base; thread rows rg + 32*r
  const int jq = (t & 7) * 4;      // col quads jq + 32*q

  // -------- phase 0: feat = relu(concat @ initW + initb); write featG; pool 0
  {
    float acc[4][16] = {};
    for (int kc = 0; kc < 64; kc += 16) {
      __syncthreads();
#pragma unroll
      for (int u = 0; u < 2; ++u) {
        int ll = t + 256 * u;                  // 0..511
        int row = ll >> 5, c4 = (ll & 31) * 4;
        int gk = kc + row;
        float4 w = (gk < 61) ? *reinterpret_cast<const float4*>(&initW[(size_t)gk * FDIM + c4])
                             : make_float4(0.f, 0.f, 0.f, 0.f);
        *reinterpret_cast<float4*>(&WcB[row * 132 + c4]) = w;
      }
      if (kc == 0 && t < 128) bL[t] = initb[t];
      __syncthreads();
      for (int kk = 0; kk < 16; kk += 4) {
        float av[4][4];
#pragma unroll
        for (int r = 0; r < 4; ++r) {
          float4 tmp = *reinterpret_cast<const float4*>(&X[(rg + 32 * r) * 68 + kc + kk]);
          av[r][0] = tmp.x; av[r][1] = tmp.y; av[r][2] = tmp.z; av[r][3] = tmp.w;
        }
#pragma unroll
        for (int c = 0; c < 4; ++c) {
          float4 w0 = *reinterpret_cast<const float4*>(&WcB[(kk + c) * 132 + jq]);
          float4 w1 = *reinterpret_cast<const float4*>(&WcB[(kk + c) * 132 + 32 + jq]);
          float4 w2 = *reinterpret_cast<const float4*>(&WcB[(kk + c) * 132 + 64 + jq]);
          float4 w3 = *reinterpret_cast<const float4*>(&WcB[(kk + c) * 132 + 96 + jq]);
#pragma unroll
          for (int r = 0; r < 4; ++r) {
            float a = av[r][c];
            acc[r][0]  += a * w0.x; acc[r][1]  += a * w0.y; acc[r][2]  += a * w0.z; acc[r][3]  += a * w0.w;
            acc[r][4]  += a * w1.x; acc[r][5]  += a * w1.y; acc[r][6]  += a * w1.z; acc[r][7]  += a * w1.w;
            acc[r][8]  += a * w2.x; acc[r][9]  += a * w2.y; acc[r][10] += a * w2.z; acc[r][11] += a * w2.w;
            acc[r][12] += a * w3.x; acc[r][13] += a * w3.y; acc[r][14] += a * w3.z; acc[r][15] += a * w3.w;
          }
        }
      }
    }
    __syncthreads();   // all concat reads done -> safe to overwrite X
#pragma unroll
    for (int r = 0; r < 4; ++r) {
      int row = rg + 32 * r;
#pragma unroll
      for (int q = 0; q < 4; ++q) {
        int col = q * 32 + jq;
        float4 bl = *reinterpret_cast<const float4*>(&bL[col]);
        float4 o = make_float4(fmaxf(acc[r][q * 4 + 0] + bl.x, 0.f),
                               fmaxf(acc[r][q * 4 + 1] + bl.y, 0.f),
                               fmaxf(acc[r][q * 4 + 2] + bl.z, 0.f),
                               fmaxf(acc[r][q * 4 + 3] + bl.w, 0.f));
        *reinterpret_cast<float4*>(&X[row * 132 + col]) = o;
        *reinterpret_cast<float4*>(&featG[(size_t)(nb + row) * FDIM + col]) = o;
      }
    }
    __syncthreads();
  }

  // -------- pool helper (256 threads: 8 row-groups x 16 rows)
#define POOL_LAYER(layer)                                                            \
  {                                                                                  \
    int j4 = (t & 31) * 4, qq = t >> 5;                                              \
    float4 pv = side ? make_float4(-INFINITY, -INFINITY, -INFINITY, -INFINITY)       \
                     : make_float4(0.f, 0.f, 0.f, 0.f);                              \
    for (int r = 0; r < 16; ++r) {                                                   \
      float4 fv = *reinterpret_cast<const float4*>(&X[(qq * 16 + r) * 132 + j4]);    \
      if (side) { pv.x = fmaxf(pv.x, fv.x); pv.y = fmaxf(pv.y, fv.y);                \
                  pv.z = fmaxf(pv.z, fv.z); pv.w = fmaxf(pv.w, fv.w); }              \
      else      { pv.x += fv.x; pv.y += fv.y; pv.z += fv.z; pv.w += fv.w; }          \
    }                                                                                \
    *reinterpret_cast<float4*>(&WcB[qq * 128 + j4]) = pv;                            \
    __syncthreads();                                                                 \
    if (t < 128) {                                                                   \
      float v = side ? -INFINITY : 0.f;                                              \
      for (int q2 = 0; q2 < 8; ++q2) {                                               \
        float w2 = WcB[q2 * 128 + t];                                                \
        v = side ? fmaxf(v, w2) : (v + w2);                                          \
      }                                                                              \
      gfs[g * 1024 + side * 512 + (layer) * 128 + t] = v;                            \
    }                                                                                \
  }

  POOL_LAYER(0)

  // -------- 3 conv layers
  for (int l = 0; l < 3; ++l) {
    const float* Wg = (l == 0) ? W1 : (l == 1) ? W2 : W3;   // SGPR select
    const float* bg = (l == 0) ? b1 : (l == 1) ? b2 : b3;
    if (t < 128) bL[t] = bg[t];     // read after the mm-end barrier below
    // mm: h = (l>0 ? relu(X) : X) @ W_l ; W streamed from L2, NO barriers
    float acc[4][16] = {};
#pragma unroll 4
    for (int k0 = 0; k0 < 128; k0 += 4) {
      float av[4][4];
#pragma unroll
      for (int r = 0; r < 4; ++r) {
        float4 tmp = *reinterpret_cast<const float4*>(&X[(rg + 32 * r) * 132 + k0]);
        if (l > 0) {
          tmp.x = fmaxf(tmp.x, 0.f); tmp.y = fmaxf(tmp.y, 0.f);
          tmp.z = fmaxf(tmp.z, 0.f); tmp.w = fmaxf(tmp.w, 0.f);
        }
        av[r][0] = tmp.x; av[r][1] = tmp.y; av[r][2] = tmp.z; av[r][3] = tmp.w;
      }
#pragma unroll
      for (int c = 0; c < 4; ++c) {
        const float* wr = Wg + (size_t)(k0 + c) * FDIM;
        float4 w0 = *reinterpret_cast<const float4*>(&wr[jq]);
        float4 w1 = *reinterpret_cast<const float4*>(&wr[32 + jq]);
        float4 w2 = *reinterpret_cast<const float4*>(&wr[64 + jq]);
        float4 w3 = *reinterpret_cast<const float4*>(&wr[96 + jq]);
#pragma unroll
        for (int r = 0; r < 4; ++r) {
          float a = av[r][c];
          acc[r][0]  += a * w0.x; acc[r][1]  += a * w0.y; acc[r][2]  += a * w0.z; acc[r][3]  += a * w0.w;
          acc[r][4]  += a * w1.x; acc[r][5]  += a * w1.y; acc[r][6]  += a * w1.z; acc[r][7]  += a * w1.w;
          acc[r][8]  += a * w2.x; acc[r][9]  += a * w2.y; acc[r][10] += a * w2.z; acc[r][11] += a * w2.w;
          acc[r][12] += a * w3.x; acc[r][13] += a * w3.y; acc[r][14] += a * w3.z; acc[r][15] += a * w3.w;
        }
      }
    }
    __syncthreads();   // all reads of X(feat) done (mm + pool); bL visible
#pragma unroll
    for (int r = 0; r < 4; ++r) {
      int row = rg + 32 * r;
#pragma unroll
      for (int q = 0; q < 4; ++q) {
        int col = q * 32 + jq;
        *reinterpret_cast<float4*>(&X[row * 132 + col]) =
            make_float4(acc[r][q * 4 + 0], acc[r][q * 4 + 1],
                        acc[r][q * 4 + 2], acc[r][q * 4 + 3]);
      }
    }
    __syncthreads();   // h complete

    // gather into regs: feat[d][f] = b[f] + dd*(dd*h[d][f] + sum_s dinv[s]*h[s][f])
    {
      int d = t >> 1, fc = (t & 1) * 64;   // 2 threads/node, 64 cols each
      float dd = dvL[d];
      float4 a[16];
#pragma unroll
      for (int u = 0; u < 16; ++u) {
        float4 hv = *reinterpret_cast<const float4*>(&X[d * 132 + fc + u * 4]);
        a[u] = make_float4(dd * hv.x, dd * hv.y, dd * hv.z, dd * hv.w);
      }
      int o0 = oL[d], o1 = enL[d];
      // prefetch-by-1 from L2-resident CSR
      int sj = (o0 < o1) ? (csrg[e_base + o0] - nb) : 0;
      for (int j = o0; j < o1; ++j) {
        int sn = (j + 1 < o1) ? (csrg[e_base + j + 1] - nb) : 0;
        float w = dvL[sj];
#pragma unroll
        for (int u = 0; u < 16; ++u) {
          float4 hv = *reinterpret_cast<const float4*>(&X[sj * 132 + fc + u * 4]);
          a[u].x += w * hv.x; a[u].y += w * hv.y; a[u].z += w * hv.z; a[u].w += w * hv.w;
        }
        sj = sn;
      }
      __syncthreads();   // all h reads done -> overwrite X with feat
#pragma unroll
      for (int u = 0; u < 16; ++u) {
        float4 bl = *reinterpret_cast<const float4*>(&bL[fc + u * 4]);
        float4 o = make_float4(bl.x + dd * a[u].x, bl.y + dd * a[u].y,
                               bl.z + dd * a[u].z, bl.w + dd * a[u].w);
        *reinterpret_cast<float4*>(&X[d * 132 + fc + u * 4]) = o;
        if (l == 2)
          *reinterpret_cast<float4*>(&f3G[(size_t)(nb + d) * FDIM + fc + u * 4]) = o;
      }
    }
    __syncthreads();   // feat complete

    POOL_LAYER(l + 1)
  }
#undef POOL_LAYER
}

// ---------------------------------------------------------------- fused sim: S = (F1@A)@F2^T -> sinkhorn
// One block = one (sim, graph); grid 512. Verified R5 version (barrier-free
// matmul phases; X1 = full Aaff -> Y overwrite; X2 = F2^T staged once).
__global__ __launch_bounds__(1024) void k_sim(const float* __restrict__ F1s1,
                                              const float* __restrict__ F2s1,
                                              const float* __restrict__ F1s2,
                                              const float* __restrict__ F2s2,
                                              const float* __restrict__ Aaff,
                                              const int* __restrict__ topk,
                                              float* __restrict__ S1,
                                              float* __restrict__ S2) {
  __shared__ float X1[128 * 132];   // Aaff -> Y (LDS-overwrite trick)
  __shared__ float X2[128 * 132];   // F2^T (k-major)
  __shared__ float rA[16], rB[16], bc[2];

  const int t = threadIdx.x;
  const int half = blockIdx.x >> 8;
  const int b = blockIdx.x & 255;
  const float* F1b = (half ? F1s2 : F1s1) + (size_t)b * NNODE * FDIM;
  const float* F2b = (half ? F2s2 : F2s1) + (size_t)b * NNODE * FDIM;
  float* Sout = (half ? S2 : S1) + (size_t)b * NNODE * NNODE;

  // -------- stage Aaff row-major into X1 (coalesced, conflict-free)
#pragma unroll
  for (int p = 0; p < 4; ++p) {
    int fi = t + 1024 * p;            // float4 index 0..4095
    int row = fi >> 5, c4 = (fi & 31) * 4;
    *reinterpret_cast<float4*>(&X1[row * 132 + c4]) =
        *reinterpret_cast<const float4*>(&Aaff[(size_t)row * FDIM + c4]);
  }
  // -------- stage F2 transposed into X2 (one-time scattered writes, ~4-way)
  {
    int row = t >> 3;                 // 0..127 (all rows covered per p)
    int cq  = (t & 7) * 4;
#pragma unroll
    for (int p = 0; p < 4; ++p) {
      int c4 = p * 32 + cq;
      float4 v = *reinterpret_cast<const float4*>(&F2b[(size_t)row * FDIM + c4]);
      X2[(c4 + 0) * 132 + row] = v.x;
      X2[(c4 + 1) * 132 + row] = v.y;
      X2[(c4 + 2) * 132 + row] = v.z;
      X2[(c4 + 3) * 132 + row] = v.w;
    }
  }
  __syncthreads();

  const int rg = t >> 3;            // output row 0..127
  const int jq = (t & 7) * 4;
  const float* f1row = F1b + (size_t)rg * FDIM;

  float acc[16];
#pragma unroll
  for (int u = 0; u < 16; ++u) acc[u] = 0.f;

  // -------- Y = F1 @ A : av from global (L3), w from X1; no barriers
  for (int k0 = 0; k0 < 128; k0 += 4) {
    float4 a4 = *reinterpret_cast<const float4*>(&f1row[k0]);
    float av[4] = {a4.x, a4.y, a4.z, a4.w};
#pragma unroll
    for (int c = 0; c < 4; ++c) {
      const float* wb = &X1[(k0 + c) * 132];
      float4 w0 = *reinterpret_cast<const float4*>(&wb[jq]);
      float4 w1 = *reinterpret_cast<const float4*>(&wb[32 + jq]);
      float4 w2 = *reinterpret_cast<const float4*>(&wb[64 + jq]);
      float4 w3 = *reinterpret_cast<const float4*>(&wb[96 + jq]);
      float a = av[c];
      acc[0]  += a * w0.x; acc[1]  += a * w0.y; acc[2]  += a * w0.z; acc[3]  += a * w0.w;
      acc[4]  += a * w1.x; acc[5]  += a * w1.y; acc[6]  += a * w1.z; acc[7]  += a * w1.w;
      acc[8]  += a * w2.x; acc[9]  += a * w2.y; acc[10] += a * w2.z; acc[11] += a * w2.w;
      acc[12] += a * w3.x; acc[13] += a * w3.y; acc[14] += a * w3.z; acc[15] += a * w3.w;
    }
  }
  __syncthreads();                   // all A reads done -> overwrite X1 with Y
#pragma unroll
  for (int q = 0; q < 4; ++q)
    *reinterpret_cast<float4*>(&X1[rg * 132 + 32 * q + jq]) =
        make_float4(acc[q * 4 + 0], acc[q * 4 + 1], acc[q * 4 + 2], acc[q * 4 + 3]);

#pragma unroll
  for (int u = 0; u < 16; ++u) acc[u] = 0.f;
  __syncthreads();                   // Y visible; S-phase barrier-free

  // -------- S = Y @ F2^T : both operands LDS-resident, no barriers
  for (int k0 = 0; k0 < 128; k0 += 4) {
    float4 a4 = *reinterpret_cast<const float4*>(&X1[rg * 132 + k0]);
    float av[4] = {a4.x, a4.y, a4.z, a4.w};
#pragma unroll
    for (int c = 0; c < 4; ++c) {
      const float* wb = &X2[(k0 + c) * 132];
      float4 w0 = *reinterpret_cast<const float4*>(&wb[jq]);
      float4 w1 = *reinterpret_cast<const float4*>(&wb[32 + jq]);
      float4 w2 = *reinterpret_cast<const float4*>(&wb[64 + jq]);
      float4 w3 = *reinterpret_cast<const float4*>(&wb[96 + jq]);
      float a = av[c];
      acc[0]  += a * w0.x; acc[1]  += a * w0.y; acc[2]  += a * w0.z; acc[3]  += a * w0.w;
      acc[4]  += a * w1.x; acc[5]  += a * w1.y; acc[6]  += a * w1.z; acc[7]  += a * w1.w;
      acc[8]  += a * w2.x; acc[9]  += a * w2.y; acc[10] += a * w2.z; acc[11] += a * w2.w;
      acc[12] += a * w3.x; acc[13] += a * w3.y; acc[14] += a * w3.z; acc[15] += a * w3.w;
    }
  }

  // -------- sinkhorn on register-resident S (ownership-agnostic reductions)
  const int wave = t >> 6, lane = t & 63;
  {
    float mn = acc[0], mx = acc[0];
#pragma unroll
    for (int u = 1; u < 16; ++u) { mn = fminf(mn, acc[u]); mx = fmaxf(mx, acc[u]); }
    for (int off = 32; off; off >>= 1) {
      mn = fminf(mn, __shfl_down(mn, off));
      mx = fmaxf(mx, __shfl_down(mx, off));
    }
    if (lane == 0) { rA[wave] = mn; rB[wave] = mx; }
    __syncthreads();
    if (t < 16) {
      mn = rA[t]; mx = rB[t];
      for (int off = 8; off; off >>= 1) {
        mn = fminf(mn, __shfl_down(mn, off));
        mx = fmaxf(mx, __shfl_down(mx, off));
      }
      if (t == 0) { bc[0] = mn - 1.f; bc[1] = mx + 1.f; }
    }
    __syncthreads();
  }
  float a_lo = bc[0], a_hi = bc[1];

  float p[16], q[16];
#pragma unroll
  for (int u = 0; u < 16; ++u) {
    p[u] = __expf(a_lo - acc[u]);
    q[u] = __expf(acc[u] - a_hi);
  }

  const float Lf = (float)(NNODE * NNODE);
  float kt = 0.5f * (float)topk[0];

  float E0 = 1.f, E1 = 1.f, E0p = 1.f, E1p = 1.f;
  for (int it = 0; it < 6; ++it) {
    E0p = E0; E1p = E1;
    float r0 = 0.f, r1 = 0.f;
#pragma unroll
    for (int u = 0; u < 16; ++u) {
      float denom = fmaf(p[u], E0, q[u] * E1);
      float rin = __builtin_amdgcn_rcpf(denom);
      r0 = fmaf(p[u], rin, r0);
      r1 = fmaf(q[u], rin, r1);
    }
    for (int off = 32; off; off >>= 1) {
      r0 += __shfl_down(r0, off);
      r1 += __shfl_down(r1, off);
    }
    if (lane == 0) { rA[wave] = r0; rB[wave] = r1; }
    __syncthreads();
    if (t < 16) {
      r0 = rA[t]; r1 = rB[t];
      for (int off = 8; off; off >>= 1) {
        r0 += __shfl_down(r0, off);
        r1 += __shfl_down(r1, off);
      }
      if (t == 0) { bc[0] = (Lf - kt) / r0; bc[1] = kt / r1; }
    }
    __syncthreads();
    E0 = bc[0]; E1 = bc[1];
    __syncthreads();
  }

  // -------- final prob write (coalesced float4 per row)
  float* xrow = Sout + (size_t)rg * NNODE;
#pragma unroll
  for (int qd = 0; qd < 4; ++qd) {
    float o[4];
#pragma unroll
    for (int j = 0; j < 4; ++j) {
      int u = qd * 4 + j;
      float denom = fmaf(p[u], E0p, q[u] * E1p);
      o[j] = q[u] * E1 * __builtin_amdgcn_rcpf(denom);
    }
    *reinterpret_cast<float4*>(&xrow[32 * qd + jq]) = make_float4(o[0], o[1], o[2], o[3]);
  }
}

// ---------------------------------------------------------------- scoring MLP
__global__ __launch_bounds__(256) void k_mlp(const float* __restrict__ gfs,
                                             const float* __restrict__ W1,
                                             const float* __restrict__ b1,
                                             const float* __restrict__ W2,
                                             const float* __restrict__ b2,
                                             float* __restrict__ ged) {
  __shared__ float sm[1024];
  int b = blockIdx.x, t = threadIdx.x;
  const float* s = gfs + b * 1024;
#pragma unroll
  for (int qq = 0; qq < 4; ++qq) sm[t + 256 * qq] = s[t + 256 * qq];
  __syncthreads();
  int j4 = (t & 15) * 4, kp = t >> 4;
  float4 acc = make_float4(0.f, 0.f, 0.f, 0.f);
#pragma unroll 8
  for (int k = 0; k < 64; ++k) {
    float4 w = *reinterpret_cast<const float4*>(&W1[(size_t)(kp * 64 + k) * 64 + j4]);
    float sv = sm[kp * 64 + k];
    acc.x += sv * w.x; acc.y += sv * w.y; acc.z += sv * w.z; acc.w += sv * w.w;
  }
  __syncthreads();
  *reinterpret_cast<float4*>(&sm[kp * 64 + j4]) = acc;
  __syncthreads();
  if (t < 64) {
    float h = b1[t];
#pragma unroll
    for (int kp2 = 0; kp2 < 16; ++kp2) h += sm[kp2 * 64 + t];
    h = fmaxf(h, 0.f);
    float v = h * W2[t];
    for (int off = 32; off; off >>= 1) v += __shfl_down(v, off);
    if (t == 0) ged[b] = 1.f / (1.f + __expf(-(v + b2[0])));
  }
}

// ================================================================ launch
extern "C" void kernel_launch(void* const* d_in, const int* in_sizes, int n_in,
                              void* d_out, int out_size, void* d_ws, size_t ws_size,
                              hipStream_t stream) {
  (void)in_sizes; (void)n_in; (void)out_size; (void)ws_size;
  const float* x1    = (const float*)d_in[0];
  const int*   cent1 = (const int*)  d_in[1];
  const float* rw1   = (const float*)d_in[2];
  const int*   src1  = (const int*)  d_in[3];
  const int*   dst1  = (const int*)  d_in[4];
  const float* x2    = (const float*)d_in[5];
  const int*   cent2 = (const int*)  d_in[6];
  const float* rw2   = (const float*)d_in[7];
  const int*   src2  = (const int*)  d_in[8];
  const int*   dst2  = (const int*)  d_in[9];
  const float* demb  = (const float*)d_in[10];
  const float* initW = (const float*)d_in[11];
  const float* initb = (const float*)d_in[12];
  const float* W1    = (const float*)d_in[13];
  const float* b1    = (const float*)d_in[14];
  const float* W2    = (const float*)d_in[15];
  const float* b2    = (const float*)d_in[16];
  const float* W3    = (const float*)d_in[17];
  const float* b3    = (const float*)d_in[18];
  const float* Aaff  = (const float*)d_in[19];
  const float* scW1  = (const float*)d_in[20];
  const float* scb1  = (const float*)d_in[21];
  const float* scW2  = (const float*)d_in[22];
  const float* scb2  = (const float*)d_in[23];
  const int*   topk  = (const int*)  d_in[24];

  float* ws    = (float*)d_ws;
  float* feat1 = ws;
  float* feat2 = ws + (size_t)1 * NTF;
  float* f13   = ws + (size_t)2 * NTF;
  float* f23   = ws + (size_t)3 * NTF;
  float* dinv1 = ws + (size_t)4 * NTF;
  float* dinv2 = dinv1 + NT;
  float* gfs   = dinv2 + NT;

  float* ged = (float*)d_out;
  float* S1  = ged + BATCH;
  float* S2  = S1 + (size_t)BATCH * NNODE * NNODE;

  // int scratch lives in S1's output region (only written by k_sim AFTER chain)
  // size: 6*NT + 2*BATCH*ESTRIDE = 196608 + 1048576 ints < S1's 4.19M floats
  int* degi1 = (int*)S1;
  int* ofs1  = degi1 + NT;
  int* cur1  = ofs1 + NT;
  int* csr1  = cur1 + NT;
  int* degi2 = csr1 + BATCH * ESTRIDE;
  int* ofs2  = degi2 + NT;
  int* cur2  = ofs2 + NT;
  int* csr2  = cur2 + NT;

  const int gE = NEDGE / 256;

  // CSR + degree norms (3 dispatches + 2 DMA memsets)
  hipMemsetAsync(degi1, 0, NT * sizeof(int), stream);
  hipMemsetAsync(degi2, 0, NT * sizeof(int), stream);
  k_deg2<<<2 * gE, 256, 0, stream>>>(dst1, dst2, degi1, degi2);
  k_scanl<<<512, 128, 0, stream>>>(degi1, ofs1, cur1, dinv1, degi2, ofs2, cur2, dinv2);
  k_fill2<<<2 * gE, 256, 0, stream>>>(src1, dst1, cur1, csr1, src2, dst2, cur2, csr2);

  // fused conv chains (both sides), writes feat1/feat2/f13/f23/gfs
  k_chain<<<512, 256, 0, stream>>>(
      x1, cent1, rw1, x2, cent2, rw2, demb, initW, initb,
      W1, b1, W2, b2, W3, b3,
      ofs1, cur1, csr1, ofs2, cur2, csr2, dinv1, dinv2,
      feat1, feat2, f13, f23, gfs);

  // ged (only needs gfs; fills the gap right after chain)
  k_mlp<<<BATCH, 256, 0, stream>>>(gfs, scW1, scb1, scW2, scb2, ged);

  // both sims in one grid-512 launch
  k_sim<<<512, 1024, 0, stream>>>(feat1, feat2, f13, f23, Aaff, topk, S1, S2);
}

// Round 7
// 419.201 us; speedup vs baseline: 1.6922x; 1.6922x over previous
//
#include <hip/hip_runtime.h>
#include <math.h>

#define BATCH 256
#define NNODE 128
#define NT    32768      // BATCH*NNODE
#define FDIM  128
#define NEDGE 262144
#define LBL   29
#define MAXDEG 16
#define RWD   16
#define NTF   (NT * FDIM)
#define ESTRIDE 2048     // per-graph CSR slot (mean 1024, sigma 32 -> 32-sigma margin)

// ---------------------------------------------------------------- CSR build (side-fused)
__global__ void k_deg2(const int* __restrict__ dst1, const int* __restrict__ dst2,
                       int* __restrict__ d1, int* __restrict__ d2) {
  int e = blockIdx.x * 256 + threadIdx.x;
  if (e < NEDGE) atomicAdd(&d1[dst1[e]], 1);
  else if (e < 2 * NEDGE) atomicAdd(&d2[dst2[e - NEDGE]], 1);
}
// per-graph local scan + dinv: one block per (side, graph), fully parallel
__global__ __launch_bounds__(128) void k_scanl(const int* __restrict__ degi1,
                                               int* __restrict__ ofs1, int* __restrict__ cur1,
                                               float* __restrict__ dinv1,
                                               const int* __restrict__ degi2,
                                               int* __restrict__ ofs2, int* __restrict__ cur2,
                                               float* __restrict__ dinv2) {
  const int side = blockIdx.x >> 8;
  const int g = blockIdx.x & 255;
  const int* degi = side ? degi2 : degi1;
  int* ofs   = side ? ofs2  : ofs1;
  int* cur   = side ? cur2  : cur1;
  float* dnv = side ? dinv2 : dinv1;
  const int t = threadIdx.x;
  const int node = g * NNODE + t;
  int dg = degi[node];
  dnv[node] = rsqrtf((float)(dg + 1));   // +1 self loop
  // inclusive scan over 128 threads (2 waves)
  int lane = t & 63, wv = t >> 6;
  int v = dg;
  for (int off = 1; off < 64; off <<= 1) {
    int u = __shfl_up(v, off);
    if (lane >= off) v += u;
  }
  __shared__ int wsum[2];
  if (lane == 63) wsum[wv] = v;
  __syncthreads();
  int excl = v - dg + (wv ? wsum[0] : 0);
  int base = g * ESTRIDE + excl;
  ofs[node] = base;
  cur[node] = base;
}
__global__ void k_fill2(const int* __restrict__ src1, const int* __restrict__ dst1,
                        int* __restrict__ cur1, int* __restrict__ csr1,
                        const int* __restrict__ src2, const int* __restrict__ dst2,
                        int* __restrict__ cur2, int* __restrict__ csr2) {
  int e = blockIdx.x * 256 + threadIdx.x;
  if (e < NEDGE) {
    int pos = atomicAdd(&cur1[dst1[e]], 1);
    csr1[pos] = src1[e];
  } else if (e < 2 * NEDGE) {
    e -= NEDGE;
    int pos = atomicAdd(&cur2[dst2[e]], 1);
    csr2[pos] = src2[e];
  }
}

// ---------------------------------------------------------------- fused per-graph chain
// One block = one (graph, side). 256 threads, 78336 B LDS -> 2 blocks/CU.
// EXACT R2/R4/R5 verified version (172.6-176.5 us, FETCH 8.76 MB, VGPR 108).
// FROZEN: (a) R3 W-prefetch -> +24% FETCH, +4.4 us; (b) R6 global-W
// streaming -> register spill, FETCH 409 MB, WRITE 1 GB, 466 us. The mm
// phase MUST keep W in LDS with short register lifetimes.
__global__ __launch_bounds__(256, 2) void k_chain(
    const float* __restrict__ x1, const int* __restrict__ cent1, const float* __restrict__ rw1,
    const float* __restrict__ x2, const int* __restrict__ cent2, const float* __restrict__ rw2,
    const float* __restrict__ demb,
    const float* __restrict__ initW, const float* __restrict__ initb,
    const float* __restrict__ W1, const float* __restrict__ b1,
    const float* __restrict__ W2, const float* __restrict__ b2,
    const float* __restrict__ W3, const float* __restrict__ b3,
    const int* __restrict__ ofs1, const int* __restrict__ end1, const int* __restrict__ csr1,
    const int* __restrict__ ofs2, const int* __restrict__ end2, const int* __restrict__ csr2,
    const float* __restrict__ dinv1, const float* __restrict__ dinv2,
    float* __restrict__ feat1G, float* __restrict__ feat2G,
    float* __restrict__ f13G, float* __restrict__ f23G,
    float* __restrict__ gfs) {
  __shared__ float X[128 * 132];      // 67584 B: concat / feat / h (phase-shared)
  __shared__ float WcB[16 * 132];     // 8448 B: W chunk (16 k-rows) / pool tmp [8*128]
  __shared__ float dvL[128];
  __shared__ float bL[128];
  __shared__ int   oL[128], enL[128];

  const int t = threadIdx.x;
  const int side = blockIdx.x >> 8;
  const int g = blockIdx.x & 255;
  const int nb = g * NNODE;

  const float* xg    = side ? x2 : x1;
  const int*   centg = side ? cent2 : cent1;
  const float* rwg   = side ? rw2 : rw1;
  const int*   ofsg  = side ? ofs2 : ofs1;
  const int*   endg  = side ? end2 : end1;
  const int*   csrg  = side ? csr2 : csr1;
  const float* dinvg = side ? dinv2 : dinv1;
  float* featG = side ? feat2G : feat1G;
  float* f3G   = side ? f23G : f13G;

  // -------- phase -1: stage dinv / csr offsets / concat features into X
  const int e_base = ofsg[nb];
  if (t < 128) {
    dvL[t] = dinvg[nb + t];
    oL[t]  = ofsg[nb + t] - e_base;
    enL[t] = endg[nb + t] - e_base;
  }
  {
    int d = t >> 1, sub = t & 1;          // 2 threads per node, 34 cols each
    int node = nb + d;
    int ct = centg[node];
    const float* xr = xg + (size_t)node * LBL;
    const float* er = demb + ct * MAXDEG;
    const float* rr = rwg + (size_t)node * RWD;
    for (int c = sub * 34; c < sub * 34 + 34; ++c) {
      float v = 0.f;
      if (c < LBL) v = xr[c];
      else if (c < LBL + MAXDEG) v = er[c - LBL];
      else if (c < 61) v = rr[c - 45];
      X[d * 68 + c] = v;                  // concat overlay, stride 68
    }
  }
  __syncthreads();

  const int rg = t >> 3;           // row base; thread rows rg + 32*r
  const int jq = (t & 7) * 4;      // col quads jq + 32*q

  // -------- phase 0: feat = relu(concat @ initW + initb); write featG; pool 0
  {
    float acc[4][16] = {};
    for (int kc = 0; kc < 64; kc += 16) {
      __syncthreads();
#pragma unroll
      for (int u = 0; u < 2; ++u) {
        int ll = t + 256 * u;                  // 0..511
        int row = ll >> 5, c4 = (ll & 31) * 4;
        int gk = kc + row;
        float4 w = (gk < 61) ? *reinterpret_cast<const float4*>(&initW[(size_t)gk * FDIM + c4])
                             : make_float4(0.f, 0.f, 0.f, 0.f);
        *reinterpret_cast<float4*>(&WcB[row * 132 + c4]) = w;
      }
      if (kc == 0 && t < 128) bL[t] = initb[t];
      __syncthreads();
      for (int kk = 0; kk < 16; kk += 4) {
        float av[4][4];
#pragma unroll
        for (int r = 0; r < 4; ++r) {
          float4 tmp = *reinterpret_cast<const float4*>(&X[(rg + 32 * r) * 68 + kc + kk]);
          av[r][0] = tmp.x; av[r][1] = tmp.y; av[r][2] = tmp.z; av[r][3] = tmp.w;
        }
#pragma unroll
        for (int c = 0; c < 4; ++c) {
          float4 w0 = *reinterpret_cast<const float4*>(&WcB[(kk + c) * 132 + jq]);
          float4 w1 = *reinterpret_cast<const float4*>(&WcB[(kk + c) * 132 + 32 + jq]);
          float4 w2 = *reinterpret_cast<const float4*>(&WcB[(kk + c) * 132 + 64 + jq]);
          float4 w3 = *reinterpret_cast<const float4*>(&WcB[(kk + c) * 132 + 96 + jq]);
#pragma unroll
          for (int r = 0; r < 4; ++r) {
            float a = av[r][c];
            acc[r][0]  += a * w0.x; acc[r][1]  += a * w0.y; acc[r][2]  += a * w0.z; acc[r][3]  += a * w0.w;
            acc[r][4]  += a * w1.x; acc[r][5]  += a * w1.y; acc[r][6]  += a * w1.z; acc[r][7]  += a * w1.w;
            acc[r][8]  += a * w2.x; acc[r][9]  += a * w2.y; acc[r][10] += a * w2.z; acc[r][11] += a * w2.w;
            acc[r][12] += a * w3.x; acc[r][13] += a * w3.y; acc[r][14] += a * w3.z; acc[r][15] += a * w3.w;
          }
        }
      }
    }
    __syncthreads();   // all concat reads done -> safe to overwrite X
#pragma unroll
    for (int r = 0; r < 4; ++r) {
      int row = rg + 32 * r;
#pragma unroll
      for (int q = 0; q < 4; ++q) {
        int col = q * 32 + jq;
        float4 bl = *reinterpret_cast<const float4*>(&bL[col]);
        float4 o = make_float4(fmaxf(acc[r][q * 4 + 0] + bl.x, 0.f),
                               fmaxf(acc[r][q * 4 + 1] + bl.y, 0.f),
                               fmaxf(acc[r][q * 4 + 2] + bl.z, 0.f),
                               fmaxf(acc[r][q * 4 + 3] + bl.w, 0.f));
        *reinterpret_cast<float4*>(&X[row * 132 + col]) = o;
        *reinterpret_cast<float4*>(&featG[(size_t)(nb + row) * FDIM + col]) = o;
      }
    }
    __syncthreads();
  }

  // -------- pool helper (256 threads: 8 row-groups x 16 rows)
#define POOL_LAYER(layer)                                                            \
  {                                                                                  \
    int j4 = (t & 31) * 4, qq = t >> 5;                                              \
    float4 pv = side ? make_float4(-INFINITY, -INFINITY, -INFINITY, -INFINITY)       \
                     : make_float4(0.f, 0.f, 0.f, 0.f);                              \
    for (int r = 0; r < 16; ++r) {                                                   \
      float4 fv = *reinterpret_cast<const float4*>(&X[(qq * 16 + r) * 132 + j4]);    \
      if (side) { pv.x = fmaxf(pv.x, fv.x); pv.y = fmaxf(pv.y, fv.y);                \
                  pv.z = fmaxf(pv.z, fv.z); pv.w = fmaxf(pv.w, fv.w); }              \
      else      { pv.x += fv.x; pv.y += fv.y; pv.z += fv.z; pv.w += fv.w; }          \
    }                                                                                \
    *reinterpret_cast<float4*>(&WcB[qq * 128 + j4]) = pv;                            \
    __syncthreads();                                                                 \
    if (t < 128) {                                                                   \
      float v = side ? -INFINITY : 0.f;                                              \
      for (int q2 = 0; q2 < 8; ++q2) {                                               \
        float w2 = WcB[q2 * 128 + t];                                                \
        v = side ? fmaxf(v, w2) : (v + w2);                                          \
      }                                                                              \
      gfs[g * 1024 + side * 512 + (layer) * 128 + t] = v;                            \
    }                                                                                \
  }

  POOL_LAYER(0)

  // -------- 3 conv layers
  for (int l = 0; l < 3; ++l) {
    const float* Wg = (l == 0) ? W1 : (l == 1) ? W2 : W3;   // SGPR select
    const float* bg = (l == 0) ? b1 : (l == 1) ? b2 : b3;
    // mm: h = (l>0 ? relu(X) : X) @ W_l   (acc in regs)
    float acc[4][16] = {};
    for (int kc = 0; kc < 128; kc += 16) {
      __syncthreads();   // protects WcB (pool tmp / prev chunk)
#pragma unroll
      for (int u = 0; u < 2; ++u) {
        int ll = t + 256 * u;
        int row = ll >> 5, c4 = (ll & 31) * 4;
        *reinterpret_cast<float4*>(&WcB[row * 132 + c4]) =
            *reinterpret_cast<const float4*>(&Wg[(size_t)(kc + row) * FDIM + c4]);
      }
      if (kc == 0 && t < 128) bL[t] = bg[t];
      __syncthreads();
      for (int kk = 0; kk < 16; kk += 4) {
        float av[4][4];
#pragma unroll
        for (int r = 0; r < 4; ++r) {
          float4 tmp = *reinterpret_cast<const float4*>(&X[(rg + 32 * r) * 132 + kc + kk]);
          if (l > 0) {
            tmp.x = fmaxf(tmp.x, 0.f); tmp.y = fmaxf(tmp.y, 0.f);
            tmp.z = fmaxf(tmp.z, 0.f); tmp.w = fmaxf(tmp.w, 0.f);
          }
          av[r][0] = tmp.x; av[r][1] = tmp.y; av[r][2] = tmp.z; av[r][3] = tmp.w;
        }
#pragma unroll
        for (int c = 0; c < 4; ++c) {
          float4 w0 = *reinterpret_cast<const float4*>(&WcB[(kk + c) * 132 + jq]);
          float4 w1 = *reinterpret_cast<const float4*>(&WcB[(kk + c) * 132 + 32 + jq]);
          float4 w2 = *reinterpret_cast<const float4*>(&WcB[(kk + c) * 132 + 64 + jq]);
          float4 w3 = *reinterpret_cast<const float4*>(&WcB[(kk + c) * 132 + 96 + jq]);
#pragma unroll
          for (int r = 0; r < 4; ++r) {
            float a = av[r][c];
            acc[r][0]  += a * w0.x; acc[r][1]  += a * w0.y; acc[r][2]  += a * w0.z; acc[r][3]  += a * w0.w;
            acc[r][4]  += a * w1.x; acc[r][5]  += a * w1.y; acc[r][6]  += a * w1.z; acc[r][7]  += a * w1.w;
            acc[r][8]  += a * w2.x; acc[r][9]  += a * w2.y; acc[r][10] += a * w2.z; acc[r][11] += a * w2.w;
            acc[r][12] += a * w3.x; acc[r][13] += a * w3.y; acc[r][14] += a * w3.z; acc[r][15] += a * w3.w;
          }
        }
      }
    }
    __syncthreads();   // all reads of X(feat) done -> overwrite with h
#pragma unroll
    for (int r = 0; r < 4; ++r) {
      int row = rg + 32 * r;
#pragma unroll
      for (int q = 0; q < 4; ++q) {
        int col = q * 32 + jq;
        *reinterpret_cast<float4*>(&X[row * 132 + col]) =
            make_float4(acc[r][q * 4 + 0], acc[r][q * 4 + 1],
                        acc[r][q * 4 + 2], acc[r][q * 4 + 3]);
      }
    }
    __syncthreads();   // h complete

    // gather into regs: feat[d][f] = b[f] + dd*(dd*h[d][f] + sum_s dinv[s]*h[s][f])
    {
      int d = t >> 1, fc = (t & 1) * 64;   // 2 threads/node, 64 cols each
      float dd = dvL[d];
      float4 a[16];
#pragma unroll
      for (int u = 0; u < 16; ++u) {
        float4 hv = *reinterpret_cast<const float4*>(&X[d * 132 + fc + u * 4]);
        a[u] = make_float4(dd * hv.x, dd * hv.y, dd * hv.z, dd * hv.w);
      }
      int o0 = oL[d], o1 = enL[d];
      // prefetch-by-1 from L2-resident CSR
      int sj = (o0 < o1) ? (csrg[e_base + o0] - nb) : 0;
      for (int j = o0; j < o1; ++j) {
        int sn = (j + 1 < o1) ? (csrg[e_base + j + 1] - nb) : 0;
        float w = dvL[sj];
#pragma unroll
        for (int u = 0; u < 16; ++u) {
          float4 hv = *reinterpret_cast<const float4*>(&X[sj * 132 + fc + u * 4]);
          a[u].x += w * hv.x; a[u].y += w * hv.y; a[u].z += w * hv.z; a[u].w += w * hv.w;
        }
        sj = sn;
      }
      __syncthreads();   // all h reads done -> overwrite X with feat
#pragma unroll
      for (int u = 0; u < 16; ++u) {
        float4 bl = *reinterpret_cast<const float4*>(&bL[fc + u * 4]);
        float4 o = make_float4(bl.x + dd * a[u].x, bl.y + dd * a[u].y,
                               bl.z + dd * a[u].z, bl.w + dd * a[u].w);
        *reinterpret_cast<float4*>(&X[d * 132 + fc + u * 4]) = o;
        if (l == 2)
          *reinterpret_cast<float4*>(&f3G[(size_t)(nb + d) * FDIM + fc + u * 4]) = o;
      }
    }
    __syncthreads();   // feat complete

    POOL_LAYER(l + 1)
  }
#undef POOL_LAYER
}

// ---------------------------------------------------------------- fused sim: S = (F1@A)@F2^T -> sinkhorn
// One block = one (sim, graph); grid 512. Verified R5 version (barrier-free
// matmul phases; X1 = full Aaff -> Y overwrite; X2 = F2^T staged once).
__global__ __launch_bounds__(1024) void k_sim(const float* __restrict__ F1s1,
                                              const float* __restrict__ F2s1,
                                              const float* __restrict__ F1s2,
                                              const float* __restrict__ F2s2,
                                              const float* __restrict__ Aaff,
                                              const int* __restrict__ topk,
                                              float* __restrict__ S1,
                                              float* __restrict__ S2) {
  __shared__ float X1[128 * 132];   // Aaff -> Y (LDS-overwrite trick)
  __shared__ float X2[128 * 132];   // F2^T (k-major)
  __shared__ float rA[16], rB[16], bc[2];

  const int t = threadIdx.x;
  const int half = blockIdx.x >> 8;
  const int b = blockIdx.x & 255;
  const float* F1b = (half ? F1s2 : F1s1) + (size_t)b * NNODE * FDIM;
  const float* F2b = (half ? F2s2 : F2s1) + (size_t)b * NNODE * FDIM;
  float* Sout = (half ? S2 : S1) + (size_t)b * NNODE * NNODE;

  // -------- stage Aaff row-major into X1 (coalesced, conflict-free)
#pragma unroll
  for (int p = 0; p < 4; ++p) {
    int fi = t + 1024 * p;            // float4 index 0..4095
    int row = fi >> 5, c4 = (fi & 31) * 4;
    *reinterpret_cast<float4*>(&X1[row * 132 + c4]) =
        *reinterpret_cast<const float4*>(&Aaff[(size_t)row * FDIM + c4]);
  }
  // -------- stage F2 transposed into X2 (one-time scattered writes, ~4-way)
  {
    int row = t >> 3;                 // 0..127 (all rows covered per p)
    int cq  = (t & 7) * 4;
#pragma unroll
    for (int p = 0; p < 4; ++p) {
      int c4 = p * 32 + cq;
      float4 v = *reinterpret_cast<const float4*>(&F2b[(size_t)row * FDIM + c4]);
      X2[(c4 + 0) * 132 + row] = v.x;
      X2[(c4 + 1) * 132 + row] = v.y;
      X2[(c4 + 2) * 132 + row] = v.z;
      X2[(c4 + 3) * 132 + row] = v.w;
    }
  }
  __syncthreads();

  const int rg = t >> 3;            // output row 0..127
  const int jq = (t & 7) * 4;
  const float* f1row = F1b + (size_t)rg * FDIM;

  float acc[16];
#pragma unroll
  for (int u = 0; u < 16; ++u) acc[u] = 0.f;

  // -------- Y = F1 @ A : av from global (L3), w from X1; no barriers
  for (int k0 = 0; k0 < 128; k0 += 4) {
    float4 a4 = *reinterpret_cast<const float4*>(&f1row[k0]);
    float av[4] = {a4.x, a4.y, a4.z, a4.w};
#pragma unroll
    for (int c = 0; c < 4; ++c) {
      const float* wb = &X1[(k0 + c) * 132];
      float4 w0 = *reinterpret_cast<const float4*>(&wb[jq]);
      float4 w1 = *reinterpret_cast<const float4*>(&wb[32 + jq]);
      float4 w2 = *reinterpret_cast<const float4*>(&wb[64 + jq]);
      float4 w3 = *reinterpret_cast<const float4*>(&wb[96 + jq]);
      float a = av[c];
      acc[0]  += a * w0.x; acc[1]  += a * w0.y; acc[2]  += a * w0.z; acc[3]  += a * w0.w;
      acc[4]  += a * w1.x; acc[5]  += a * w1.y; acc[6]  += a * w1.z; acc[7]  += a * w1.w;
      acc[8]  += a * w2.x; acc[9]  += a * w2.y; acc[10] += a * w2.z; acc[11] += a * w2.w;
      acc[12] += a * w3.x; acc[13] += a * w3.y; acc[14] += a * w3.z; acc[15] += a * w3.w;
    }
  }
  __syncthreads();                   // all A reads done -> overwrite X1 with Y
#pragma unroll
  for (int q = 0; q < 4; ++q)
    *reinterpret_cast<float4*>(&X1[rg * 132 + 32 * q + jq]) =
        make_float4(acc[q * 4 + 0], acc[q * 4 + 1], acc[q * 4 + 2], acc[q * 4 + 3]);

#pragma unroll
  for (int u = 0; u < 16; ++u) acc[u] = 0.f;
  __syncthreads();                   // Y visible; S-phase barrier-free

  // -------- S = Y @ F2^T : both operands LDS-resident, no barriers
  for (int k0 = 0; k0 < 128; k0 += 4) {
    float4 a4 = *reinterpret_cast<const float4*>(&X1[rg * 132 + k0]);
    float av[4] = {a4.x, a4.y, a4.z, a4.w};
#pragma unroll
    for (int c = 0; c < 4; ++c) {
      const float* wb = &X2[(k0 + c) * 132];
      float4 w0 = *reinterpret_cast<const float4*>(&wb[jq]);
      float4 w1 = *reinterpret_cast<const float4*>(&wb[32 + jq]);
      float4 w2 = *reinterpret_cast<const float4*>(&wb[64 + jq]);
      float4 w3 = *reinterpret_cast<const float4*>(&wb[96 + jq]);
      float a = av[c];
      acc[0]  += a * w0.x; acc[1]  += a * w0.y; acc[2]  += a * w0.z; acc[3]  += a * w0.w;
      acc[4]  += a * w1.x; acc[5]  += a * w1.y; acc[6]  += a * w1.z; acc[7]  += a * w1.w;
      acc[8]  += a * w2.x; acc[9]  += a * w2.y; acc[10] += a * w2.z; acc[11] += a * w2.w;
      acc[12] += a * w3.x; acc[13] += a * w3.y; acc[14] += a * w3.z; acc[15] += a * w3.w;
    }
  }

  // -------- sinkhorn on register-resident S (ownership-agnostic reductions)
  const int wave = t >> 6, lane = t & 63;
  {
    float mn = acc[0], mx = acc[0];
#pragma unroll
    for (int u = 1; u < 16; ++u) { mn = fminf(mn, acc[u]); mx = fmaxf(mx, acc[u]); }
    for (int off = 32; off; off >>= 1) {
      mn = fminf(mn, __shfl_down(mn, off));
      mx = fmaxf(mx, __shfl_down(mx, off));
    }
    if (lane == 0) { rA[wave] = mn; rB[wave] = mx; }
    __syncthreads();
    if (t < 16) {
      mn = rA[t]; mx = rB[t];
      for (int off = 8; off; off >>= 1) {
        mn = fminf(mn, __shfl_down(mn, off));
        mx = fmaxf(mx, __shfl_down(mx, off));
      }
      if (t == 0) { bc[0] = mn - 1.f; bc[1] = mx + 1.f; }
    }
    __syncthreads();
  }
  float a_lo = bc[0], a_hi = bc[1];

  float p[16], q[16];
#pragma unroll
  for (int u = 0; u < 16; ++u) {
    p[u] = __expf(a_lo - acc[u]);
    q[u] = __expf(acc[u] - a_hi);
  }

  const float Lf = (float)(NNODE * NNODE);
  float kt = 0.5f * (float)topk[0];

  float E0 = 1.f, E1 = 1.f, E0p = 1.f, E1p = 1.f;
  for (int it = 0; it < 6; ++it) {
    E0p = E0; E1p = E1;
    float r0 = 0.f, r1 = 0.f;
#pragma unroll
    for (int u = 0; u < 16; ++u) {
      float denom = fmaf(p[u], E0, q[u] * E1);
      float rin = __builtin_amdgcn_rcpf(denom);
      r0 = fmaf(p[u], rin, r0);
      r1 = fmaf(q[u], rin, r1);
    }
    for (int off = 32; off; off >>= 1) {
      r0 += __shfl_down(r0, off);
      r1 += __shfl_down(r1, off);
    }
    if (lane == 0) { rA[wave] = r0; rB[wave] = r1; }
    __syncthreads();
    if (t < 16) {
      r0 = rA[t]; r1 = rB[t];
      for (int off = 8; off; off >>= 1) {
        r0 += __shfl_down(r0, off);
        r1 += __shfl_down(r1, off);
      }
      if (t == 0) { bc[0] = (Lf - kt) / r0; bc[1] = kt / r1; }
    }
    __syncthreads();
    E0 = bc[0]; E1 = bc[1];
    __syncthreads();
  }

  // -------- final prob write (coalesced float4 per row)
  float* xrow = Sout + (size_t)rg * NNODE;
#pragma unroll
  for (int qd = 0; qd < 4; ++qd) {
    float o[4];
#pragma unroll
    for (int j = 0; j < 4; ++j) {
      int u = qd * 4 + j;
      float denom = fmaf(p[u], E0p, q[u] * E1p);
      o[j] = q[u] * E1 * __builtin_amdgcn_rcpf(denom);
    }
    *reinterpret_cast<float4*>(&xrow[32 * qd + jq]) = make_float4(o[0], o[1], o[2], o[3]);
  }
}

// ---------------------------------------------------------------- scoring MLP
__global__ __launch_bounds__(256) void k_mlp(const float* __restrict__ gfs,
                                             const float* __restrict__ W1,
                                             const float* __restrict__ b1,
                                             const float* __restrict__ W2,
                                             const float* __restrict__ b2,
                                             float* __restrict__ ged) {
  __shared__ float sm[1024];
  int b = blockIdx.x, t = threadIdx.x;
  const float* s = gfs + b * 1024;
#pragma unroll
  for (int qq = 0; qq < 4; ++qq) sm[t + 256 * qq] = s[t + 256 * qq];
  __syncthreads();
  int j4 = (t & 15) * 4, kp = t >> 4;
  float4 acc = make_float4(0.f, 0.f, 0.f, 0.f);
#pragma unroll 8
  for (int k = 0; k < 64; ++k) {
    float4 w = *reinterpret_cast<const float4*>(&W1[(size_t)(kp * 64 + k) * 64 + j4]);
    float sv = sm[kp * 64 + k];
    acc.x += sv * w.x; acc.y += sv * w.y; acc.z += sv * w.z; acc.w += sv * w.w;
  }
  __syncthreads();
  *reinterpret_cast<float4*>(&sm[kp * 64 + j4]) = acc;
  __syncthreads();
  if (t < 64) {
    float h = b1[t];
#pragma unroll
    for (int kp2 = 0; kp2 < 16; ++kp2) h += sm[kp2 * 64 + t];
    h = fmaxf(h, 0.f);
    float v = h * W2[t];
    for (int off = 32; off; off >>= 1) v += __shfl_down(v, off);
    if (t == 0) ged[b] = 1.f / (1.f + __expf(-(v + b2[0])));
  }
}

// ================================================================ launch
extern "C" void kernel_launch(void* const* d_in, const int* in_sizes, int n_in,
                              void* d_out, int out_size, void* d_ws, size_t ws_size,
                              hipStream_t stream) {
  (void)in_sizes; (void)n_in; (void)out_size; (void)ws_size;
  const float* x1    = (const float*)d_in[0];
  const int*   cent1 = (const int*)  d_in[1];
  const float* rw1   = (const float*)d_in[2];
  const int*   src1  = (const int*)  d_in[3];
  const int*   dst1  = (const int*)  d_in[4];
  const float* x2    = (const float*)d_in[5];
  const int*   cent2 = (const int*)  d_in[6];
  const float* rw2   = (const float*)d_in[7];
  const int*   src2  = (const int*)  d_in[8];
  const int*   dst2  = (const int*)  d_in[9];
  const float* demb  = (const float*)d_in[10];
  const float* initW = (const float*)d_in[11];
  const float* initb = (const float*)d_in[12];
  const float* W1    = (const float*)d_in[13];
  const float* b1    = (const float*)d_in[14];
  const float* W2    = (const float*)d_in[15];
  const float* b2    = (const float*)d_in[16];
  const float* W3    = (const float*)d_in[17];
  const float* b3    = (const float*)d_in[18];
  const float* Aaff  = (const float*)d_in[19];
  const float* scW1  = (const float*)d_in[20];
  const float* scb1  = (const float*)d_in[21];
  const float* scW2  = (const float*)d_in[22];
  const float* scb2  = (const float*)d_in[23];
  const int*   topk  = (const int*)  d_in[24];

  float* ws    = (float*)d_ws;
  float* feat1 = ws;
  float* feat2 = ws + (size_t)1 * NTF;
  float* f13   = ws + (size_t)2 * NTF;
  float* f23   = ws + (size_t)3 * NTF;
  float* dinv1 = ws + (size_t)4 * NTF;
  float* dinv2 = dinv1 + NT;
  float* gfs   = dinv2 + NT;

  float* ged = (float*)d_out;
  float* S1  = ged + BATCH;
  float* S2  = S1 + (size_t)BATCH * NNODE * NNODE;

  // int scratch lives in S1's output region (only written by k_sim AFTER chain)
  // size: 6*NT + 2*BATCH*ESTRIDE ints < S1's 4.19M floats
  int* degi1 = (int*)S1;
  int* ofs1  = degi1 + NT;
  int* cur1  = ofs1 + NT;
  int* csr1  = cur1 + NT;
  int* degi2 = csr1 + BATCH * ESTRIDE;
  int* ofs2  = degi2 + NT;
  int* cur2  = ofs2 + NT;
  int* csr2  = ofs2 + 2 * NT;

  const int gE = NEDGE / 256;

  // CSR + degree norms (3 dispatches + 2 DMA memsets)
  hipMemsetAsync(degi1, 0, NT * sizeof(int), stream);
  hipMemsetAsync(degi2, 0, NT * sizeof(int), stream);
  k_deg2<<<2 * gE, 256, 0, stream>>>(dst1, dst2, degi1, degi2);
  k_scanl<<<512, 128, 0, stream>>>(degi1, ofs1, cur1, dinv1, degi2, ofs2, cur2, dinv2);
  k_fill2<<<2 * gE, 256, 0, stream>>>(src1, dst1, cur1, csr1, src2, dst2, cur2, csr2);

  // fused conv chains (both sides), writes feat1/feat2/f13/f23/gfs
  k_chain<<<512, 256, 0, stream>>>(
      x1, cent1, rw1, x2, cent2, rw2, demb, initW, initb,
      W1, b1, W2, b2, W3, b3,
      ofs1, cur1, csr1, ofs2, cur2, csr2, dinv1, dinv2,
      feat1, feat2, f13, f23, gfs);

  // ged (only needs gfs; fills the gap right after chain)
  k_mlp<<<BATCH, 256, 0, stream>>>(gfs, scW1, scb1, scW2, scb2, ged);

  // both sims in one grid-512 launch
  k_sim<<<512, 1024, 0, stream>>>(feat1, feat2, f13, f23, Aaff, topk, S1, S2);
}

// Round 8
// 413.899 us; speedup vs baseline: 1.7139x; 1.0128x over previous
//
#include <hip/hip_runtime.h>
#include <math.h>

#define BATCH 256
#define NNODE 128
#define NT    32768      // BATCH*NNODE
#define FDIM  128
#define NEDGE 262144
#define LBL   29
#define MAXDEG 16
#define RWD   16
#define NTF   (NT * FDIM)
#define ESTRIDE 2048     // per-graph CSR slot (mean 1024, sigma 32 -> 32-sigma margin)

// ---------------------------------------------------------------- CSR build (side-fused)
__global__ void k_deg2(const int* __restrict__ dst1, const int* __restrict__ dst2,
                       int* __restrict__ d1, int* __restrict__ d2) {
  int e = blockIdx.x * 256 + threadIdx.x;
  if (e < NEDGE) atomicAdd(&d1[dst1[e]], 1);
  else if (e < 2 * NEDGE) atomicAdd(&d2[dst2[e - NEDGE]], 1);
}
// per-graph local scan + dinv: one block per (side, graph), fully parallel
// (verified R7: replaced 2-block global scan, -23.6 us)
__global__ __launch_bounds__(128) void k_scanl(const int* __restrict__ degi1,
                                               int* __restrict__ ofs1, int* __restrict__ cur1,
                                               float* __restrict__ dinv1,
                                               const int* __restrict__ degi2,
                                               int* __restrict__ ofs2, int* __restrict__ cur2,
                                               float* __restrict__ dinv2) {
  const int side = blockIdx.x >> 8;
  const int g = blockIdx.x & 255;
  const int* degi = side ? degi2 : degi1;
  int* ofs   = side ? ofs2  : ofs1;
  int* cur   = side ? cur2  : cur1;
  float* dnv = side ? dinv2 : dinv1;
  const int t = threadIdx.x;
  const int node = g * NNODE + t;
  int dg = degi[node];
  dnv[node] = rsqrtf((float)(dg + 1));   // +1 self loop
  // inclusive scan over 128 threads (2 waves)
  int lane = t & 63, wv = t >> 6;
  int v = dg;
  for (int off = 1; off < 64; off <<= 1) {
    int u = __shfl_up(v, off);
    if (lane >= off) v += u;
  }
  __shared__ int wsum[2];
  if (lane == 63) wsum[wv] = v;
  __syncthreads();
  int excl = v - dg + (wv ? wsum[0] : 0);
  int base = g * ESTRIDE + excl;
  ofs[node] = base;
  cur[node] = base;
}
__global__ void k_fill2(const int* __restrict__ src1, const int* __restrict__ dst1,
                        int* __restrict__ cur1, int* __restrict__ csr1,
                        const int* __restrict__ src2, const int* __restrict__ dst2,
                        int* __restrict__ cur2, int* __restrict__ csr2) {
  int e = blockIdx.x * 256 + threadIdx.x;
  if (e < NEDGE) {
    int pos = atomicAdd(&cur1[dst1[e]], 1);
    csr1[pos] = src1[e];
  } else if (e < 2 * NEDGE) {
    e -= NEDGE;
    int pos = atomicAdd(&cur2[dst2[e]], 1);
    csr2[pos] = src2[e];
  }
}

// ---------------------------------------------------------------- fused per-graph chain
// One block = one (graph, side). 256 threads, 78336 B LDS -> 2 blocks/CU.
// EXACT R2/R4/R5/R7 verified version (172.6-176.5 us, FETCH 8.76 MB, VGPR 108).
// FROZEN: (a) R3 W-prefetch -> +24% FETCH, +4.4 us; (b) R6 global-W
// streaming -> register spill, FETCH 409 MB, WRITE 1 GB, 466 us. The mm
// phase MUST keep W in LDS with short register lifetimes.
__global__ __launch_bounds__(256, 2) void k_chain(
    const float* __restrict__ x1, const int* __restrict__ cent1, const float* __restrict__ rw1,
    const float* __restrict__ x2, const int* __restrict__ cent2, const float* __restrict__ rw2,
    const float* __restrict__ demb,
    const float* __restrict__ initW, const float* __restrict__ initb,
    const float* __restrict__ W1, const float* __restrict__ b1,
    const float* __restrict__ W2, const float* __restrict__ b2,
    const float* __restrict__ W3, const float* __restrict__ b3,
    const int* __restrict__ ofs1, const int* __restrict__ end1, const int* __restrict__ csr1,
    const int* __restrict__ ofs2, const int* __restrict__ end2, const int* __restrict__ csr2,
    const float* __restrict__ dinv1, const float* __restrict__ dinv2,
    float* __restrict__ feat1G, float* __restrict__ feat2G,
    float* __restrict__ f13G, float* __restrict__ f23G,
    float* __restrict__ gfs) {
  __shared__ float X[128 * 132];      // 67584 B: concat / feat / h (phase-shared)
  __shared__ float WcB[16 * 132];     // 8448 B: W chunk (16 k-rows) / pool tmp [8*128]
  __shared__ float dvL[128];
  __shared__ float bL[128];
  __shared__ int   oL[128], enL[128];

  const int t = threadIdx.x;
  const int side = blockIdx.x >> 8;
  const int g = blockIdx.x & 255;
  const int nb = g * NNODE;

  const float* xg    = side ? x2 : x1;
  const int*   centg = side ? cent2 : cent1;
  const float* rwg   = side ? rw2 : rw1;
  const int*   ofsg  = side ? ofs2 : ofs1;
  const int*   endg  = side ? end2 : end1;
  const int*   csrg  = side ? csr2 : csr1;
  const float* dinvg = side ? dinv2 : dinv1;
  float* featG = side ? feat2G : feat1G;
  float* f3G   = side ? f23G : f13G;

  // -------- phase -1: stage dinv / csr offsets / concat features into X
  const int e_base = ofsg[nb];
  if (t < 128) {
    dvL[t] = dinvg[nb + t];
    oL[t]  = ofsg[nb + t] - e_base;
    enL[t] = endg[nb + t] - e_base;
  }
  {
    int d = t >> 1, sub = t & 1;          // 2 threads per node, 34 cols each
    int node = nb + d;
    int ct = centg[node];
    const float* xr = xg + (size_t)node * LBL;
    const float* er = demb + ct * MAXDEG;
    const float* rr = rwg + (size_t)node * RWD;
    for (int c = sub * 34; c < sub * 34 + 34; ++c) {
      float v = 0.f;
      if (c < LBL) v = xr[c];
      else if (c < LBL + MAXDEG) v = er[c - LBL];
      else if (c < 61) v = rr[c - 45];
      X[d * 68 + c] = v;                  // concat overlay, stride 68
    }
  }
  __syncthreads();

  const int rg = t >> 3;           // row base; thread rows rg + 32*r
  const int jq = (t & 7) * 4;      // col quads jq + 32*q

  // -------- phase 0: feat = relu(concat @ initW + initb); write featG; pool 0
  {
    float acc[4][16] = {};
    for (int kc = 0; kc < 64; kc += 16) {
      __syncthreads();
#pragma unroll
      for (int u = 0; u < 2; ++u) {
        int ll = t + 256 * u;                  // 0..511
        int row = ll >> 5, c4 = (ll & 31) * 4;
        int gk = kc + row;
        float4 w = (gk < 61) ? *reinterpret_cast<const float4*>(&initW[(size_t)gk * FDIM + c4])
                             : make_float4(0.f, 0.f, 0.f, 0.f);
        *reinterpret_cast<float4*>(&WcB[row * 132 + c4]) = w;
      }
      if (kc == 0 && t < 128) bL[t] = initb[t];
      __syncthreads();
      for (int kk = 0; kk < 16; kk += 4) {
        float av[4][4];
#pragma unroll
        for (int r = 0; r < 4; ++r) {
          float4 tmp = *reinterpret_cast<const float4*>(&X[(rg + 32 * r) * 68 + kc + kk]);
          av[r][0] = tmp.x; av[r][1] = tmp.y; av[r][2] = tmp.z; av[r][3] = tmp.w;
        }
#pragma unroll
        for (int c = 0; c < 4; ++c) {
          float4 w0 = *reinterpret_cast<const float4*>(&WcB[(kk + c) * 132 + jq]);
          float4 w1 = *reinterpret_cast<const float4*>(&WcB[(kk + c) * 132 + 32 + jq]);
          float4 w2 = *reinterpret_cast<const float4*>(&WcB[(kk + c) * 132 + 64 + jq]);
          float4 w3 = *reinterpret_cast<const float4*>(&WcB[(kk + c) * 132 + 96 + jq]);
#pragma unroll
          for (int r = 0; r < 4; ++r) {
            float a = av[r][c];
            acc[r][0]  += a * w0.x; acc[r][1]  += a * w0.y; acc[r][2]  += a * w0.z; acc[r][3]  += a * w0.w;
            acc[r][4]  += a * w1.x; acc[r][5]  += a * w1.y; acc[r][6]  += a * w1.z; acc[r][7]  += a * w1.w;
            acc[r][8]  += a * w2.x; acc[r][9]  += a * w2.y; acc[r][10] += a * w2.z; acc[r][11] += a * w2.w;
            acc[r][12] += a * w3.x; acc[r][13] += a * w3.y; acc[r][14] += a * w3.z; acc[r][15] += a * w3.w;
          }
        }
      }
    }
    __syncthreads();   // all concat reads done -> safe to overwrite X
#pragma unroll
    for (int r = 0; r < 4; ++r) {
      int row = rg + 32 * r;
#pragma unroll
      for (int q = 0; q < 4; ++q) {
        int col = q * 32 + jq;
        float4 bl = *reinterpret_cast<const float4*>(&bL[col]);
        float4 o = make_float4(fmaxf(acc[r][q * 4 + 0] + bl.x, 0.f),
                               fmaxf(acc[r][q * 4 + 1] + bl.y, 0.f),
                               fmaxf(acc[r][q * 4 + 2] + bl.z, 0.f),
                               fmaxf(acc[r][q * 4 + 3] + bl.w, 0.f));
        *reinterpret_cast<float4*>(&X[row * 132 + col]) = o;
        *reinterpret_cast<float4*>(&featG[(size_t)(nb + row) * FDIM + col]) = o;
      }
    }
    __syncthreads();
  }

  // -------- pool helper (256 threads: 8 row-groups x 16 rows)
#define POOL_LAYER(layer)                                                            \
  {                                                                                  \
    int j4 = (t & 31) * 4, qq = t >> 5;                                              \
    float4 pv = side ? make_float4(-INFINITY, -INFINITY, -INFINITY, -INFINITY)       \
                     : make_float4(0.f, 0.f, 0.f, 0.f);                              \
    for (int r = 0; r < 16; ++r) {                                                   \
      float4 fv = *reinterpret_cast<const float4*>(&X[(qq * 16 + r) * 132 + j4]);    \
      if (side) { pv.x = fmaxf(pv.x, fv.x); pv.y = fmaxf(pv.y, fv.y);                \
                  pv.z = fmaxf(pv.z, fv.z); pv.w = fmaxf(pv.w, fv.w); }              \
      else      { pv.x += fv.x; pv.y += fv.y; pv.z += fv.z; pv.w += fv.w; }          \
    }                                                                                \
    *reinterpret_cast<float4*>(&WcB[qq * 128 + j4]) = pv;                            \
    __syncthreads();                                                                 \
    if (t < 128) {                                                                   \
      float v = side ? -INFINITY : 0.f;                                              \
      for (int q2 = 0; q2 < 8; ++q2) {                                               \
        float w2 = WcB[q2 * 128 + t];                                                \
        v = side ? fmaxf(v, w2) : (v + w2);                                          \
      }                                                                              \
      gfs[g * 1024 + side * 512 + (layer) * 128 + t] = v;                            \
    }                                                                                \
  }

  POOL_LAYER(0)

  // -------- 3 conv layers
  for (int l = 0; l < 3; ++l) {
    const float* Wg = (l == 0) ? W1 : (l == 1) ? W2 : W3;   // SGPR select
    const float* bg = (l == 0) ? b1 : (l == 1) ? b2 : b3;
    // mm: h = (l>0 ? relu(X) : X) @ W_l   (acc in regs)
    float acc[4][16] = {};
    for (int kc = 0; kc < 128; kc += 16) {
      __syncthreads();   // protects WcB (pool tmp / prev chunk)
#pragma unroll
      for (int u = 0; u < 2; ++u) {
        int ll = t + 256 * u;
        int row = ll >> 5, c4 = (ll & 31) * 4;
        *reinterpret_cast<float4*>(&WcB[row * 132 + c4]) =
            *reinterpret_cast<const float4*>(&Wg[(size_t)(kc + row) * FDIM + c4]);
      }
      if (kc == 0 && t < 128) bL[t] = bg[t];
      __syncthreads();
      for (int kk = 0; kk < 16; kk += 4) {
        float av[4][4];
#pragma unroll
        for (int r = 0; r < 4; ++r) {
          float4 tmp = *reinterpret_cast<const float4*>(&X[(rg + 32 * r) * 132 + kc + kk]);
          if (l > 0) {
            tmp.x = fmaxf(tmp.x, 0.f); tmp.y = fmaxf(tmp.y, 0.f);
            tmp.z = fmaxf(tmp.z, 0.f); tmp.w = fmaxf(tmp.w, 0.f);
          }
          av[r][0] = tmp.x; av[r][1] = tmp.y; av[r][2] = tmp.z; av[r][3] = tmp.w;
        }
#pragma unroll
        for (int c = 0; c < 4; ++c) {
          float4 w0 = *reinterpret_cast<const float4*>(&WcB[(kk + c) * 132 + jq]);
          float4 w1 = *reinterpret_cast<const float4*>(&WcB[(kk + c) * 132 + 32 + jq]);
          float4 w2 = *reinterpret_cast<const float4*>(&WcB[(kk + c) * 132 + 64 + jq]);
          float4 w3 = *reinterpret_cast<const float4*>(&WcB[(kk + c) * 132 + 96 + jq]);
#pragma unroll
          for (int r = 0; r < 4; ++r) {
            float a = av[r][c];
            acc[r][0]  += a * w0.x; acc[r][1]  += a * w0.y; acc[r][2]  += a * w0.z; acc[r][3]  += a * w0.w;
            acc[r][4]  += a * w1.x; acc[r][5]  += a * w1.y; acc[r][6]  += a * w1.z; acc[r][7]  += a * w1.w;
            acc[r][8]  += a * w2.x; acc[r][9]  += a * w2.y; acc[r][10] += a * w2.z; acc[r][11] += a * w2.w;
            acc[r][12] += a * w3.x; acc[r][13] += a * w3.y; acc[r][14] += a * w3.z; acc[r][15] += a * w3.w;
          }
        }
      }
    }
    __syncthreads();   // all reads of X(feat) done -> overwrite with h
#pragma unroll
    for (int r = 0; r < 4; ++r) {
      int row = rg + 32 * r;
#pragma unroll
      for (int q = 0; q < 4; ++q) {
        int col = q * 32 + jq;
        *reinterpret_cast<float4*>(&X[row * 132 + col]) =
            make_float4(acc[r][q * 4 + 0], acc[r][q * 4 + 1],
                        acc[r][q * 4 + 2], acc[r][q * 4 + 3]);
      }
    }
    __syncthreads();   // h complete

    // gather into regs: feat[d][f] = b[f] + dd*(dd*h[d][f] + sum_s dinv[s]*h[s][f])
    {
      int d = t >> 1, fc = (t & 1) * 64;   // 2 threads/node, 64 cols each
      float dd = dvL[d];
      float4 a[16];
#pragma unroll
      for (int u = 0; u < 16; ++u) {
        float4 hv = *reinterpret_cast<const float4*>(&X[d * 132 + fc + u * 4]);
        a[u] = make_float4(dd * hv.x, dd * hv.y, dd * hv.z, dd * hv.w);
      }
      int o0 = oL[d], o1 = enL[d];
      // prefetch-by-1 from L2-resident CSR
      int sj = (o0 < o1) ? (csrg[e_base + o0] - nb) : 0;
      for (int j = o0; j < o1; ++j) {
        int sn = (j + 1 < o1) ? (csrg[e_base + j + 1] - nb) : 0;
        float w = dvL[sj];
#pragma unroll
        for (int u = 0; u < 16; ++u) {
          float4 hv = *reinterpret_cast<const float4*>(&X[sj * 132 + fc + u * 4]);
          a[u].x += w * hv.x; a[u].y += w * hv.y; a[u].z += w * hv.z; a[u].w += w * hv.w;
        }
        sj = sn;
      }
      __syncthreads();   // all h reads done -> overwrite X with feat
#pragma unroll
      for (int u = 0; u < 16; ++u) {
        float4 bl = *reinterpret_cast<const float4*>(&bL[fc + u * 4]);
        float4 o = make_float4(bl.x + dd * a[u].x, bl.y + dd * a[u].y,
                               bl.z + dd * a[u].z, bl.w + dd * a[u].w);
        *reinterpret_cast<float4*>(&X[d * 132 + fc + u * 4]) = o;
        if (l == 2)
          *reinterpret_cast<float4*>(&f3G[(size_t)(nb + d) * FDIM + fc + u * 4]) = o;
      }
    }
    __syncthreads();   // feat complete

    POOL_LAYER(l + 1)
  }
#undef POOL_LAYER
}

// ---------------------------------------------------------------- fused sim: S = (F1@A)@F2^T -> sinkhorn
// One block = one (sim, graph); grid 512. Barrier-free matmul phases (R5).
// THIS ROUND: thread tile re-shaped 1x16 -> 2x8 (rows {rw, rw+64} x cols
// {jq4, jq4+64}): the two rows SHARE every B-operand read, cutting LDS
// b128 reads per 4-k-group from 17 to 10 (-45% LDS issue traffic).
// Bank patterns: w-reads 2-way aliased (free, m136), av-reads 4-addr
// 16-way broadcast (free). Per-element matmul arithmetic unchanged
// (ascending k) -> bit-exact; sinkhorn reduction grouping changes ->
// E0/E1 may drift ~1 ulp (absmax stays ~1e-5).
__global__ __launch_bounds__(1024) void k_sim(const float* __restrict__ F1s1,
                                              const float* __restrict__ F2s1,
                                              const float* __restrict__ F1s2,
                                              const float* __restrict__ F2s2,
                                              const float* __restrict__ Aaff,
                                              const int* __restrict__ topk,
                                              float* __restrict__ S1,
                                              float* __restrict__ S2) {
  __shared__ float X1[128 * 132];   // Aaff -> Y (LDS-overwrite trick)
  __shared__ float X2[128 * 132];   // F2^T (k-major)
  __shared__ float rA[16], rB[16], bc[2];

  const int t = threadIdx.x;
  const int half = blockIdx.x >> 8;
  const int b = blockIdx.x & 255;
  const float* F1b = (half ? F1s2 : F1s1) + (size_t)b * NNODE * FDIM;
  const float* F2b = (half ? F2s2 : F2s1) + (size_t)b * NNODE * FDIM;
  float* Sout = (half ? S2 : S1) + (size_t)b * NNODE * NNODE;

  // -------- stage Aaff row-major into X1 (coalesced, conflict-free)
#pragma unroll
  for (int p = 0; p < 4; ++p) {
    int fi = t + 1024 * p;            // float4 index 0..4095
    int row = fi >> 5, c4 = (fi & 31) * 4;
    *reinterpret_cast<float4*>(&X1[row * 132 + c4]) =
        *reinterpret_cast<const float4*>(&Aaff[(size_t)row * FDIM + c4]);
  }
  // -------- stage F2 transposed into X2 (one-time scattered writes, ~4-way)
  {
    int row = t >> 3;                 // 0..127 (all rows covered per p)
    int cq  = (t & 7) * 4;
#pragma unroll
    for (int p = 0; p < 4; ++p) {
      int c4 = p * 32 + cq;
      float4 v = *reinterpret_cast<const float4*>(&F2b[(size_t)row * FDIM + c4]);
      X2[(c4 + 0) * 132 + row] = v.x;
      X2[(c4 + 1) * 132 + row] = v.y;
      X2[(c4 + 2) * 132 + row] = v.z;
      X2[(c4 + 3) * 132 + row] = v.w;
    }
  }
  __syncthreads();

  const int rw = t >> 4;            // row pair: rw and rw+64 (0..63)
  const int jq4 = (t & 15) * 4;     // col pair: jq4 and jq4+64
  const float* f1r0 = F1b + (size_t)rw * FDIM;
  const float* f1r1 = F1b + (size_t)(rw + 64) * FDIM;

  // acc[r][j]: r=0 -> row rw, r=1 -> row rw+64; j 0..3 -> col jq4+j,
  // j 4..7 -> col jq4+64+j-4
  float acc[2][8] = {};

  // -------- Y = F1 @ A : av from global (L3), w from X1; no barriers
  for (int k0 = 0; k0 < 128; k0 += 4) {
    float4 a40 = *reinterpret_cast<const float4*>(&f1r0[k0]);
    float4 a41 = *reinterpret_cast<const float4*>(&f1r1[k0]);
    float av0[4] = {a40.x, a40.y, a40.z, a40.w};
    float av1[4] = {a41.x, a41.y, a41.z, a41.w};
#pragma unroll
    for (int c = 0; c < 4; ++c) {
      const float* wb = &X1[(k0 + c) * 132];
      float4 w0 = *reinterpret_cast<const float4*>(&wb[jq4]);
      float4 w1 = *reinterpret_cast<const float4*>(&wb[jq4 + 64]);
      float a0 = av0[c], a1 = av1[c];
      acc[0][0] += a0 * w0.x; acc[0][1] += a0 * w0.y; acc[0][2] += a0 * w0.z; acc[0][3] += a0 * w0.w;
      acc[0][4] += a0 * w1.x; acc[0][5] += a0 * w1.y; acc[0][6] += a0 * w1.z; acc[0][7] += a0 * w1.w;
      acc[1][0] += a1 * w0.x; acc[1][1] += a1 * w0.y; acc[1][2] += a1 * w0.z; acc[1][3] += a1 * w0.w;
      acc[1][4] += a1 * w1.x; acc[1][5] += a1 * w1.y; acc[1][6] += a1 * w1.z; acc[1][7] += a1 * w1.w;
    }
  }
  __syncthreads();                   // all A reads done -> overwrite X1 with Y
  *reinterpret_cast<float4*>(&X1[rw * 132 + jq4]) =
      make_float4(acc[0][0], acc[0][1], acc[0][2], acc[0][3]);
  *reinterpret_cast<float4*>(&X1[rw * 132 + jq4 + 64]) =
      make_float4(acc[0][4], acc[0][5], acc[0][6], acc[0][7]);
  *reinterpret_cast<float4*>(&X1[(rw + 64) * 132 + jq4]) =
      make_float4(acc[1][0], acc[1][1], acc[1][2], acc[1][3]);
  *reinterpret_cast<float4*>(&X1[(rw + 64) * 132 + jq4 + 64]) =
      make_float4(acc[1][4], acc[1][5], acc[1][6], acc[1][7]);

#pragma unroll
  for (int r = 0; r < 2; ++r)
#pragma unroll
    for (int j = 0; j < 8; ++j) acc[r][j] = 0.f;
  __syncthreads();                   // Y visible; S-phase barrier-free

  // -------- S = Y @ F2^T : both operands LDS-resident, no barriers
  for (int k0 = 0; k0 < 128; k0 += 4) {
    float4 a40 = *reinterpret_cast<const float4*>(&X1[rw * 132 + k0]);
    float4 a41 = *reinterpret_cast<const float4*>(&X1[(rw + 64) * 132 + k0]);
    float av0[4] = {a40.x, a40.y, a40.z, a40.w};
    float av1[4] = {a41.x, a41.y, a41.z, a41.w};
#pragma unroll
    for (int c = 0; c < 4; ++c) {
      const float* wb = &X2[(k0 + c) * 132];
      float4 w0 = *reinterpret_cast<const float4*>(&wb[jq4]);
      float4 w1 = *reinterpret_cast<const float4*>(&wb[jq4 + 64]);
      float a0 = av0[c], a1 = av1[c];
      acc[0][0] += a0 * w0.x; acc[0][1] += a0 * w0.y; acc[0][2] += a0 * w0.z; acc[0][3] += a0 * w0.w;
      acc[0][4] += a0 * w1.x; acc[0][5] += a0 * w1.y; acc[0][6] += a0 * w1.z; acc[0][7] += a0 * w1.w;
      acc[1][0] += a1 * w0.x; acc[1][1] += a1 * w0.y; acc[1][2] += a1 * w0.z; acc[1][3] += a1 * w0.w;
      acc[1][4] += a1 * w1.x; acc[1][5] += a1 * w1.y; acc[1][6] += a1 * w1.z; acc[1][7] += a1 * w1.w;
    }
  }

  // -------- sinkhorn on register-resident S (ownership-agnostic reductions)
  const float* af = &acc[0][0];      // flat 16 values
  const int wave = t >> 6, lane = t & 63;
  {
    float mn = af[0], mx = af[0];
#pragma unroll
    for (int u = 1; u < 16; ++u) { mn = fminf(mn, af[u]); mx = fmaxf(mx, af[u]); }
    for (int off = 32; off; off >>= 1) {
      mn = fminf(mn, __shfl_down(mn, off));
      mx = fmaxf(mx, __shfl_down(mx, off));
    }
    if (lane == 0) { rA[wave] = mn; rB[wave] = mx; }
    __syncthreads();
    if (t < 16) {
      mn = rA[t]; mx = rB[t];
      for (int off = 8; off; off >>= 1) {
        mn = fminf(mn, __shfl_down(mn, off));
        mx = fmaxf(mx, __shfl_down(mx, off));
      }
      if (t == 0) { bc[0] = mn - 1.f; bc[1] = mx + 1.f; }
    }
    __syncthreads();
  }
  float a_lo = bc[0], a_hi = bc[1];

  float p[16], q[16];
#pragma unroll
  for (int u = 0; u < 16; ++u) {
    p[u] = __expf(a_lo - af[u]);
    q[u] = __expf(af[u] - a_hi);
  }

  const float Lf = (float)(NNODE * NNODE);
  float kt = 0.5f * (float)topk[0];

  float E0 = 1.f, E1 = 1.f, E0p = 1.f, E1p = 1.f;
  for (int it = 0; it < 6; ++it) {
    E0p = E0; E1p = E1;
    float r0 = 0.f, r1 = 0.f;
#pragma unroll
    for (int u = 0; u < 16; ++u) {
      float denom = fmaf(p[u], E0, q[u] * E1);
      float rin = __builtin_amdgcn_rcpf(denom);
      r0 = fmaf(p[u], rin, r0);
      r1 = fmaf(q[u], rin, r1);
    }
    for (int off = 32; off; off >>= 1) {
      r0 += __shfl_down(r0, off);
      r1 += __shfl_down(r1, off);
    }
    if (lane == 0) { rA[wave] = r0; rB[wave] = r1; }
    __syncthreads();
    if (t < 16) {
      r0 = rA[t]; r1 = rB[t];
      for (int off = 8; off; off >>= 1) {
        r0 += __shfl_down(r0, off);
        r1 += __shfl_down(r1, off);
      }
      if (t == 0) { bc[0] = (Lf - kt) / r0; bc[1] = kt / r1; }
    }
    __syncthreads();
    E0 = bc[0]; E1 = bc[1];
    __syncthreads();
  }

  // -------- final prob write (2 rows x 2 float4, coalesced per 16-lane group)
#pragma unroll
  for (int r = 0; r < 2; ++r) {
    float* xrow = Sout + (size_t)(rw + r * 64) * NNODE;
#pragma unroll
    for (int qd = 0; qd < 2; ++qd) {
      float o[4];
#pragma unroll
      for (int j = 0; j < 4; ++j) {
        int u = r * 8 + qd * 4 + j;
        float denom = fmaf(p[u], E0p, q[u] * E1p);
        o[j] = q[u] * E1 * __builtin_amdgcn_rcpf(denom);
      }
      *reinterpret_cast<float4*>(&xrow[jq4 + qd * 64]) = make_float4(o[0], o[1], o[2], o[3]);
    }
  }
}

// ---------------------------------------------------------------- scoring MLP
__global__ __launch_bounds__(256) void k_mlp(const float* __restrict__ gfs,
                                             const float* __restrict__ W1,
                                             const float* __restrict__ b1,
                                             const float* __restrict__ W2,
                                             const float* __restrict__ b2,
                                             float* __restrict__ ged) {
  __shared__ float sm[1024];
  int b = blockIdx.x, t = threadIdx.x;
  const float* s = gfs + b * 1024;
#pragma unroll
  for (int qq = 0; qq < 4; ++qq) sm[t + 256 * qq] = s[t + 256 * qq];
  __syncthreads();
  int j4 = (t & 15) * 4, kp = t >> 4;
  float4 acc = make_float4(0.f, 0.f, 0.f, 0.f);
#pragma unroll 8
  for (int k = 0; k < 64; ++k) {
    float4 w = *reinterpret_cast<const float4*>(&W1[(size_t)(kp * 64 + k) * 64 + j4]);
    float sv = sm[kp * 64 + k];
    acc.x += sv * w.x; acc.y += sv * w.y; acc.z += sv * w.z; acc.w += sv * w.w;
  }
  __syncthreads();
  *reinterpret_cast<float4*>(&sm[kp * 64 + j4]) = acc;
  __syncthreads();
  if (t < 64) {
    float h = b1[t];
#pragma unroll
    for (int kp2 = 0; kp2 < 16; ++kp2) h += sm[kp2 * 64 + t];
    h = fmaxf(h, 0.f);
    float v = h * W2[t];
    for (int off = 32; off; off >>= 1) v += __shfl_down(v, off);
    if (t == 0) ged[b] = 1.f / (1.f + __expf(-(v + b2[0])));
  }
}

// ================================================================ launch
extern "C" void kernel_launch(void* const* d_in, const int* in_sizes, int n_in,
                              void* d_out, int out_size, void* d_ws, size_t ws_size,
                              hipStream_t stream) {
  (void)in_sizes; (void)n_in; (void)out_size; (void)ws_size;
  const float* x1    = (const float*)d_in[0];
  const int*   cent1 = (const int*)  d_in[1];
  const float* rw1   = (const float*)d_in[2];
  const int*   src1  = (const int*)  d_in[3];
  const int*   dst1  = (const int*)  d_in[4];
  const float* x2    = (const float*)d_in[5];
  const int*   cent2 = (const int*)  d_in[6];
  const float* rw2   = (const float*)d_in[7];
  const int*   src2  = (const int*)  d_in[8];
  const int*   dst2  = (const int*)  d_in[9];
  const float* demb  = (const float*)d_in[10];
  const float* initW = (const float*)d_in[11];
  const float* initb = (const float*)d_in[12];
  const float* W1    = (const float*)d_in[13];
  const float* b1    = (const float*)d_in[14];
  const float* W2    = (const float*)d_in[15];
  const float* b2    = (const float*)d_in[16];
  const float* W3    = (const float*)d_in[17];
  const float* b3    = (const float*)d_in[18];
  const float* Aaff  = (const float*)d_in[19];
  const float* scW1  = (const float*)d_in[20];
  const float* scb1  = (const float*)d_in[21];
  const float* scW2  = (const float*)d_in[22];
  const float* scb2  = (const float*)d_in[23];
  const int*   topk  = (const int*)  d_in[24];

  float* ws    = (float*)d_ws;
  float* feat1 = ws;
  float* feat2 = ws + (size_t)1 * NTF;
  float* f13   = ws + (size_t)2 * NTF;
  float* f23   = ws + (size_t)3 * NTF;
  float* dinv1 = ws + (size_t)4 * NTF;
  float* dinv2 = dinv1 + NT;
  float* gfs   = dinv2 + NT;

  float* ged = (float*)d_out;
  float* S1  = ged + BATCH;
  float* S2  = S1 + (size_t)BATCH * NNODE * NNODE;

  // int scratch lives in S1's output region (only written by k_sim AFTER chain)
  int* degi1 = (int*)S1;
  int* ofs1  = degi1 + NT;
  int* cur1  = ofs1 + NT;
  int* csr1  = cur1 + NT;
  int* degi2 = csr1 + BATCH * ESTRIDE;
  int* ofs2  = degi2 + NT;
  int* cur2  = ofs2 + NT;
  int* csr2  = ofs2 + 2 * NT;

  const int gE = NEDGE / 256;

  // CSR + degree norms (3 dispatches + 2 DMA memsets)
  hipMemsetAsync(degi1, 0, NT * sizeof(int), stream);
  hipMemsetAsync(degi2, 0, NT * sizeof(int), stream);
  k_deg2<<<2 * gE, 256, 0, stream>>>(dst1, dst2, degi1, degi2);
  k_scanl<<<512, 128, 0, stream>>>(degi1, ofs1, cur1, dinv1, degi2, ofs2, cur2, dinv2);
  k_fill2<<<2 * gE, 256, 0, stream>>>(src1, dst1, cur1, csr1, src2, dst2, cur2, csr2);

  // fused conv chains (both sides), writes feat1/feat2/f13/f23/gfs
  k_chain<<<512, 256, 0, stream>>>(
      x1, cent1, rw1, x2, cent2, rw2, demb, initW, initb,
      W1, b1, W2, b2, W3, b3,
      ofs1, cur1, csr1, ofs2, cur2, csr2, dinv1, dinv2,
      feat1, feat2, f13, f23, gfs);

  // ged (only needs gfs; fills the gap right after chain)
  k_mlp<<<BATCH, 256, 0, stream>>>(gfs, scW1, scb1, scW2, scb2, ged);

  // both sims in one grid-512 launch
  k_sim<<<512, 1024, 0, stream>>>(feat1, feat2, f13, f23, Aaff, topk, S1, S2);
}

// Round 10
// 391.253 us; speedup vs baseline: 1.8131x; 1.0579x over previous
//
#include <hip/hip_runtime.h>
#include <math.h>

#define BATCH 256
#define NNODE 128
#define NT    32768      // BATCH*NNODE
#define FDIM  128
#define NEDGE 262144
#define LBL   29
#define MAXDEG 16
#define RWD   16
#define NTF   (NT * FDIM)
#define DSLOT 64         // per-node CSR bucket (in-degree ~ Poisson(8); P(>64) ~ e^-60)

// ---------------------------------------------------------------- CSR build: direct bucket fill
// No degree-count pass, no scan: each node owns a DSLOT-int slot; fill
// appends via atomicAdd on cnt. Degree = cnt (consumed by k_chain for dinv).
__global__ void k_fill(const int* __restrict__ src1, const int* __restrict__ dst1,
                       int* __restrict__ cnt1, int* __restrict__ csr1,
                       const int* __restrict__ src2, const int* __restrict__ dst2,
                       int* __restrict__ cnt2, int* __restrict__ csr2) {
  int e = blockIdx.x * 256 + threadIdx.x;
  if (e < NEDGE) {
    int node = dst1[e];
    int pos = atomicAdd(&cnt1[node], 1);
    csr1[(size_t)node * DSLOT + pos] = src1[e];
  } else if (e < 2 * NEDGE) {
    e -= NEDGE;
    int node = dst2[e];
    int pos = atomicAdd(&cnt2[node], 1);
    csr2[(size_t)node * DSLOT + pos] = src2[e];
  }
}

// ---------------------------------------------------------------- fused per-graph chain
// One block = one (graph, side). 256 threads, ~78 KB LDS -> 2 blocks/CU.
// Compute structure = EXACT R2/R4/R5/R7/R8 verified version (172.6-178.5 us,
// FETCH 8.76 MB, VGPR 108). FROZEN: (a) R3 W-prefetch -> +24% FETCH, +4.4 us;
// (b) R6 global-W streaming -> register spill, 466 us. mm keeps W in LDS.
// R9 change: phase -1 only -- dinv computed from cnt (rsqrtf), gather reads
// from fixed-stride bucket CSR (same volume, contiguous per node).
__global__ __launch_bounds__(256, 2) void k_chain(
    const float* __restrict__ x1, const int* __restrict__ cent1, const float* __restrict__ rw1,
    const float* __restrict__ x2, const int* __restrict__ cent2, const float* __restrict__ rw2,
    const float* __restrict__ demb,
    const float* __restrict__ initW, const float* __restrict__ initb,
    const float* __restrict__ W1, const float* __restrict__ b1,
    const float* __restrict__ W2, const float* __restrict__ b2,
    const float* __restrict__ W3, const float* __restrict__ b3,
    const int* __restrict__ cnt1, const int* __restrict__ csr1,
    const int* __restrict__ cnt2, const int* __restrict__ csr2,
    float* __restrict__ feat1G, float* __restrict__ feat2G,
    float* __restrict__ f13G, float* __restrict__ f23G,
    float* __restrict__ gfs) {
  __shared__ float X[128 * 132];      // 67584 B: concat / feat / h (phase-shared)
  __shared__ float WcB[16 * 132];     // 8448 B: W chunk (16 k-rows) / pool tmp [8*128]
  __shared__ float dvL[128];
  __shared__ float bL[128];
  __shared__ int   cnL[128];

  const int t = threadIdx.x;
  const int side = blockIdx.x >> 8;
  const int g = blockIdx.x & 255;
  const int nb = g * NNODE;

  const float* xg    = side ? x2 : x1;
  const int*   centg = side ? cent2 : cent1;
  const float* rwg   = side ? rw2 : rw1;
  const int*   cntg  = side ? cnt2 : cnt1;
  const int*   csrg  = side ? csr2 : csr1;
  float* featG = side ? feat2G : feat1G;
  float* f3G   = side ? f23G : f13G;

  // -------- phase -1: stage degree->dinv / concat features into X
  if (t < 128) {
    int dg = cntg[nb + t];
    dvL[t] = rsqrtf((float)(dg + 1));   // +1 self loop
    cnL[t] = dg;
  }
  {
    int d = t >> 1, sub = t & 1;          // 2 threads per node, 34 cols each
    int node = nb + d;
    int ct = centg[node];
    const float* xr = xg + (size_t)node * LBL;
    const float* er = demb + ct * MAXDEG;
    const float* rr = rwg + (size_t)node * RWD;
    for (int c = sub * 34; c < sub * 34 + 34; ++c) {
      float v = 0.f;
      if (c < LBL) v = xr[c];
      else if (c < LBL + MAXDEG) v = er[c - LBL];
      else if (c < 61) v = rr[c - 45];
      X[d * 68 + c] = v;                  // concat overlay, stride 68
    }
  }
  __syncthreads();

  const int rg = t >> 3;           // row base; thread rows rg + 32*r
  const int jq = (t & 7) * 4;      // col quads jq + 32*q

  // -------- phase 0: feat = relu(concat @ initW + initb); write featG; pool 0
  {
    float acc[4][16] = {};
    for (int kc = 0; kc < 64; kc += 16) {
      __syncthreads();
#pragma unroll
      for (int u = 0; u < 2; ++u) {
        int ll = t + 256 * u;                  // 0..511
        int row = ll >> 5, c4 = (ll & 31) * 4;
        int gk = kc + row;
        float4 w = (gk < 61) ? *reinterpret_cast<const float4*>(&initW[(size_t)gk * FDIM + c4])
                             : make_float4(0.f, 0.f, 0.f, 0.f);
        *reinterpret_cast<float4*>(&WcB[row * 132 + c4]) = w;
      }
      if (kc == 0 && t < 128) bL[t] = initb[t];
      __syncthreads();
      for (int kk = 0; kk < 16; kk += 4) {
        float av[4][4];
#pragma unroll
        for (int r = 0; r < 4; ++r) {
          float4 tmp = *reinterpret_cast<const float4*>(&X[(rg + 32 * r) * 68 + kc + kk]);
          av[r][0] = tmp.x; av[r][1] = tmp.y; av[r][2] = tmp.z; av[r][3] = tmp.w;
        }
#pragma unroll
        for (int c = 0; c < 4; ++c) {
          float4 w0 = *reinterpret_cast<const float4*>(&WcB[(kk + c) * 132 + jq]);
          float4 w1 = *reinterpret_cast<const float4*>(&WcB[(kk + c) * 132 + 32 + jq]);
          float4 w2 = *reinterpret_cast<const float4*>(&WcB[(kk + c) * 132 + 64 + jq]);
          float4 w3 = *reinterpret_cast<const float4*>(&WcB[(kk + c) * 132 + 96 + jq]);
#pragma unroll
          for (int r = 0; r < 4; ++r) {
            float a = av[r][c];
            acc[r][0]  += a * w0.x; acc[r][1]  += a * w0.y; acc[r][2]  += a * w0.z; acc[r][3]  += a * w0.w;
            acc[r][4]  += a * w1.x; acc[r][5]  += a * w1.y; acc[r][6]  += a * w1.z; acc[r][7]  += a * w1.w;
            acc[r][8]  += a * w2.x; acc[r][9]  += a * w2.y; acc[r][10] += a * w2.z; acc[r][11] += a * w2.w;
            acc[r][12] += a * w3.x; acc[r][13] += a * w3.y; acc[r][14] += a * w3.z; acc[r][15] += a * w3.w;
          }
        }
      }
    }
    __syncthreads();   // all concat reads done -> safe to overwrite X
#pragma unroll
    for (int r = 0; r < 4; ++r) {
      int row = rg + 32 * r;
#pragma unroll
      for (int q = 0; q < 4; ++q) {
        int col = q * 32 + jq;
        float4 bl = *reinterpret_cast<const float4*>(&bL[col]);
        float4 o = make_float4(fmaxf(acc[r][q * 4 + 0] + bl.x, 0.f),
                               fmaxf(acc[r][q * 4 + 1] + bl.y, 0.f),
                               fmaxf(acc[r][q * 4 + 2] + bl.z, 0.f),
                               fmaxf(acc[r][q * 4 + 3] + bl.w, 0.f));
        *reinterpret_cast<float4*>(&X[row * 132 + col]) = o;
        *reinterpret_cast<float4*>(&featG[(size_t)(nb + row) * FDIM + col]) = o;
      }
    }
    __syncthreads();
  }

  // -------- pool helper (256 threads: 8 row-groups x 16 rows)
#define POOL_LAYER(layer)                                                            \
  {                                                                                  \
    int j4 = (t & 31) * 4, qq = t >> 5;                                              \
    float4 pv = side ? make_float4(-INFINITY, -INFINITY, -INFINITY, -INFINITY)       \
                     : make_float4(0.f, 0.f, 0.f, 0.f);                              \
    for (int r = 0; r < 16; ++r) {                                                   \
      float4 fv = *reinterpret_cast<const float4*>(&X[(qq * 16 + r) * 132 + j4]);    \
      if (side) { pv.x = fmaxf(pv.x, fv.x); pv.y = fmaxf(pv.y, fv.y);                \
                  pv.z = fmaxf(pv.z, fv.z); pv.w = fmaxf(pv.w, fv.w); }              \
      else      { pv.x += fv.x; pv.y += fv.y; pv.z += fv.z; pv.w += fv.w; }          \
    }                                                                                \
    *reinterpret_cast<float4*>(&WcB[qq * 128 + j4]) = pv;                            \
    __syncthreads();                                                                 \
    if (t < 128) {                                                                   \
      float v = side ? -INFINITY : 0.f;                                              \
      for (int q2 = 0; q2 < 8; ++q2) {                                               \
        float w2 = WcB[q2 * 128 + t];                                                \
        v = side ? fmaxf(v, w2) : (v + w2);                                          \
      }                                                                              \
      gfs[g * 1024 + side * 512 + (layer) * 128 + t] = v;                            \
    }                                                                                \
  }

  POOL_LAYER(0)

  // -------- 3 conv layers
  for (int l = 0; l < 3; ++l) {
    const float* Wg = (l == 0) ? W1 : (l == 1) ? W2 : W3;   // SGPR select
    const float* bg = (l == 0) ? b1 : (l == 1) ? b2 : b3;
    // mm: h = (l>0 ? relu(X) : X) @ W_l   (acc in regs)
    float acc[4][16] = {};
    for (int kc = 0; kc < 128; kc += 16) {
      __syncthreads();   // protects WcB (pool tmp / prev chunk)
#pragma unroll
      for (int u = 0; u < 2; ++u) {
        int ll = t + 256 * u;
        int row = ll >> 5, c4 = (ll & 31) * 4;
        *reinterpret_cast<float4*>(&WcB[row * 132 + c4]) =
            *reinterpret_cast<const float4*>(&Wg[(size_t)(kc + row) * FDIM + c4]);
      }
      if (kc == 0 && t < 128) bL[t] = bg[t];
      __syncthreads();
      for (int kk = 0; kk < 16; kk += 4) {
        float av[4][4];
#pragma unroll
        for (int r = 0; r < 4; ++r) {
          float4 tmp = *reinterpret_cast<const float4*>(&X[(rg + 32 * r) * 132 + kc + kk]);
          if (l > 0) {
            tmp.x = fmaxf(tmp.x, 0.f); tmp.y = fmaxf(tmp.y, 0.f);
            tmp.z = fmaxf(tmp.z, 0.f); tmp.w = fmaxf(tmp.w, 0.f);
          }
          av[r][0] = tmp.x; av[r][1] = tmp.y; av[r][2] = tmp.z; av[r][3] = tmp.w;
        }
#pragma unroll
        for (int c = 0; c < 4; ++c) {
          float4 w0 = *reinterpret_cast<const float4*>(&WcB[(kk + c) * 132 + jq]);
          float4 w1 = *reinterpret_cast<const float4*>(&WcB[(kk + c) * 132 + 32 + jq]);
          float4 w2 = *reinterpret_cast<const float4*>(&WcB[(kk + c) * 132 + 64 + jq]);
          float4 w3 = *reinterpret_cast<const float4*>(&WcB[(kk + c) * 132 + 96 + jq]);
#pragma unroll
          for (int r = 0; r < 4; ++r) {
            float a = av[r][c];
            acc[r][0]  += a * w0.x; acc[r][1]  += a * w0.y; acc[r][2]  += a * w0.z; acc[r][3]  += a * w0.w;
            acc[r][4]  += a * w1.x; acc[r][5]  += a * w1.y; acc[r][6]  += a * w1.z; acc[r][7]  += a * w1.w;
            acc[r][8]  += a * w2.x; acc[r][9]  += a * w2.y; acc[r][10] += a * w2.z; acc[r][11] += a * w2.w;
            acc[r][12] += a * w3.x; acc[r][13] += a * w3.y; acc[r][14] += a * w3.z; acc[r][15] += a * w3.w;
          }
        }
      }
    }
    __syncthreads();   // all reads of X(feat) done -> overwrite with h
#pragma unroll
    for (int r = 0; r < 4; ++r) {
      int row = rg + 32 * r;
#pragma unroll
      for (int q = 0; q < 4; ++q) {
        int col = q * 32 + jq;
        *reinterpret_cast<float4*>(&X[row * 132 + col]) =
            make_float4(acc[r][q * 4 + 0], acc[r][q * 4 + 1],
                        acc[r][q * 4 + 2], acc[r][q * 4 + 3]);
      }
    }
    __syncthreads();   // h complete

    // gather into regs: feat[d][f] = b[f] + dd*(dd*h[d][f] + sum_s dinv[s]*h[s][f])
    {
      int d = t >> 1, fc = (t & 1) * 64;   // 2 threads/node, 64 cols each
      float dd = dvL[d];
      float4 a[16];
#pragma unroll
      for (int u = 0; u < 16; ++u) {
        float4 hv = *reinterpret_cast<const float4*>(&X[d * 132 + fc + u * 4]);
        a[u] = make_float4(dd * hv.x, dd * hv.y, dd * hv.z, dd * hv.w);
      }
      const int* elist = csrg + (size_t)(nb + d) * DSLOT;
      int cntd = cnL[d];
      // prefetch-by-1 from L2-resident bucket CSR
      int sj = (cntd > 0) ? (elist[0] - nb) : 0;
      for (int j = 0; j < cntd; ++j) {
        int sn = (j + 1 < cntd) ? (elist[j + 1] - nb) : 0;
        float w = dvL[sj];
#pragma unroll
        for (int u = 0; u < 16; ++u) {
          float4 hv = *reinterpret_cast<const float4*>(&X[sj * 132 + fc + u * 4]);
          a[u].x += w * hv.x; a[u].y += w * hv.y; a[u].z += w * hv.z; a[u].w += w * hv.w;
        }
        sj = sn;
      }
      __syncthreads();   // all h reads done -> overwrite X with feat
#pragma unroll
      for (int u = 0; u < 16; ++u) {
        float4 bl = *reinterpret_cast<const float4*>(&bL[fc + u * 4]);
        float4 o = make_float4(bl.x + dd * a[u].x, bl.y + dd * a[u].y,
                               bl.z + dd * a[u].z, bl.w + dd * a[u].w);
        *reinterpret_cast<float4*>(&X[d * 132 + fc + u * 4]) = o;
        if (l == 2)
          *reinterpret_cast<float4*>(&f3G[(size_t)(nb + d) * FDIM + fc + u * 4]) = o;
      }
    }
    __syncthreads();   // feat complete

    POOL_LAYER(l + 1)
  }
#undef POOL_LAYER
}

// ---------------------------------------------------------------- fused sim: S = (F1@A)@F2^T -> sinkhorn
// One block = one (sim, graph); grid 512. Barrier-free matmul phases (R5);
// 2x8 thread tile (R8, shared B-reads). Unchanged.
__global__ __launch_bounds__(1024) void k_sim(const float* __restrict__ F1s1,
                                              const float* __restrict__ F2s1,
                                              const float* __restrict__ F1s2,
                                              const float* __restrict__ F2s2,
                                              const float* __restrict__ Aaff,
                                              const int* __restrict__ topk,
                                              float* __restrict__ S1,
                                              float* __restrict__ S2) {
  __shared__ float X1[128 * 132];   // Aaff -> Y (LDS-overwrite trick)
  __shared__ float X2[128 * 132];   // F2^T (k-major)
  __shared__ float rA[16], rB[16], bc[2];

  const int t = threadIdx.x;
  const int half = blockIdx.x >> 8;
  const int b = blockIdx.x & 255;
  const float* F1b = (half ? F1s2 : F1s1) + (size_t)b * NNODE * FDIM;
  const float* F2b = (half ? F2s2 : F2s1) + (size_t)b * NNODE * FDIM;
  float* Sout = (half ? S2 : S1) + (size_t)b * NNODE * NNODE;

  // -------- stage Aaff row-major into X1 (coalesced, conflict-free)
#pragma unroll
  for (int p = 0; p < 4; ++p) {
    int fi = t + 1024 * p;            // float4 index 0..4095
    int row = fi >> 5, c4 = (fi & 31) * 4;
    *reinterpret_cast<float4*>(&X1[row * 132 + c4]) =
        *reinterpret_cast<const float4*>(&Aaff[(size_t)row * FDIM + c4]);
  }
  // -------- stage F2 transposed into X2 (one-time scattered writes, ~4-way)
  {
    int row = t >> 3;                 // 0..127 (all rows covered per p)
    int cq  = (t & 7) * 4;
#pragma unroll
    for (int p = 0; p < 4; ++p) {
      int c4 = p * 32 + cq;
      float4 v = *reinterpret_cast<const float4*>(&F2b[(size_t)row * FDIM + c4]);
      X2[(c4 + 0) * 132 + row] = v.x;
      X2[(c4 + 1) * 132 + row] = v.y;
      X2[(c4 + 2) * 132 + row] = v.z;
      X2[(c4 + 3) * 132 + row] = v.w;
    }
  }
  __syncthreads();

  const int rw = t >> 4;            // row pair: rw and rw+64 (0..63)
  const int jq4 = (t & 15) * 4;     // col pair: jq4 and jq4+64
  const float* f1r0 = F1b + (size_t)rw * FDIM;
  const float* f1r1 = F1b + (size_t)(rw + 64) * FDIM;

  float acc[2][8] = {};

  // -------- Y = F1 @ A : av from global (L3), w from X1; no barriers
  for (int k0 = 0; k0 < 128; k0 += 4) {
    float4 a40 = *reinterpret_cast<const float4*>(&f1r0[k0]);
    float4 a41 = *reinterpret_cast<const float4*>(&f1r1[k0]);
    float av0[4] = {a40.x, a40.y, a40.z, a40.w};
    float av1[4] = {a41.x, a41.y, a41.z, a41.w};
#pragma unroll
    for (int c = 0; c < 4; ++c) {
      const float* wb = &X1[(k0 + c) * 132];
      float4 w0 = *reinterpret_cast<const float4*>(&wb[jq4]);
      float4 w1 = *reinterpret_cast<const float4*>(&wb[jq4 + 64]);
      float a0 = av0[c], a1 = av1[c];
      acc[0][0] += a0 * w0.x; acc[0][1] += a0 * w0.y; acc[0][2] += a0 * w0.z; acc[0][3] += a0 * w0.w;
      acc[0][4] += a0 * w1.x; acc[0][5] += a0 * w1.y; acc[0][6] += a0 * w1.z; acc[0][7] += a0 * w1.w;
      acc[1][0] += a1 * w0.x; acc[1][1] += a1 * w0.y; acc[1][2] += a1 * w0.z; acc[1][3] += a1 * w0.w;
      acc[1][4] += a1 * w1.x; acc[1][5] += a1 * w1.y; acc[1][6] += a1 * w1.z; acc[1][7] += a1 * w1.w;
    }
  }
  __syncthreads();                   // all A reads done -> overwrite X1 with Y
  *reinterpret_cast<float4*>(&X1[rw * 132 + jq4]) =
      make_float4(acc[0][0], acc[0][1], acc[0][2], acc[0][3]);
  *reinterpret_cast<float4*>(&X1[rw * 132 + jq4 + 64]) =
      make_float4(acc[0][4], acc[0][5], acc[0][6], acc[0][7]);
  *reinterpret_cast<float4*>(&X1[(rw + 64) * 132 + jq4]) =
      make_float4(acc[1][0], acc[1][1], acc[1][2], acc[1][3]);
  *reinterpret_cast<float4*>(&X1[(rw + 64) * 132 + jq4 + 64]) =
      make_float4(acc[1][4], acc[1][5], acc[1][6], acc[1][7]);

#pragma unroll
  for (int r = 0; r < 2; ++r)
#pragma unroll
    for (int j = 0; j < 8; ++j) acc[r][j] = 0.f;
  __syncthreads();                   // Y visible; S-phase barrier-free

  // -------- S = Y @ F2^T : both operands LDS-resident, no barriers
  for (int k0 = 0; k0 < 128; k0 += 4) {
    float4 a40 = *reinterpret_cast<const float4*>(&X1[rw * 132 + k0]);
    float4 a41 = *reinterpret_cast<const float4*>(&X1[(rw + 64) * 132 + k0]);
    float av0[4] = {a40.x, a40.y, a40.z, a40.w};
    float av1[4] = {a41.x, a41.y, a41.z, a41.w};
#pragma unroll
    for (int c = 0; c < 4; ++c) {
      const float* wb = &X2[(k0 + c) * 132];
      float4 w0 = *reinterpret_cast<const float4*>(&wb[jq4]);
      float4 w1 = *reinterpret_cast<const float4*>(&wb[jq4 + 64]);
      float a0 = av0[c], a1 = av1[c];
      acc[0][0] += a0 * w0.x; acc[0][1] += a0 * w0.y; acc[0][2] += a0 * w0.z; acc[0][3] += a0 * w0.w;
      acc[0][4] += a0 * w1.x; acc[0][5] += a0 * w1.y; acc[0][6] += a0 * w1.z; acc[0][7] += a0 * w1.w;
      acc[1][0] += a1 * w0.x; acc[1][1] += a1 * w0.y; acc[1][2] += a1 * w0.z; acc[1][3] += a1 * w0.w;
      acc[1][4] += a1 * w1.x; acc[1][5] += a1 * w1.y; acc[1][6] += a1 * w1.z; acc[1][7] += a1 * w1.w;
    }
  }

  // -------- sinkhorn on register-resident S (ownership-agnostic reductions)
  const float* af = &acc[0][0];      // flat 16 values
  const int wave = t >> 6, lane = t & 63;
  {
    float mn = af[0], mx = af[0];
#pragma unroll
    for (int u = 1; u < 16; ++u) { mn = fminf(mn, af[u]); mx = fmaxf(mx, af[u]); }
    for (int off = 32; off; off >>= 1) {
      mn = fminf(mn, __shfl_down(mn, off));
      mx = fmaxf(mx, __shfl_down(mx, off));
    }
    if (lane == 0) { rA[wave] = mn; rB[wave] = mx; }
    __syncthreads();
    if (t < 16) {
      mn = rA[t]; mx = rB[t];
      for (int off = 8; off; off >>= 1) {
        mn = fminf(mn, __shfl_down(mn, off));
        mx = fmaxf(mx, __shfl_down(mx, off));
      }
      if (t == 0) { bc[0] = mn - 1.f; bc[1] = mx + 1.f; }
    }
    __syncthreads();
  }
  float a_lo = bc[0], a_hi = bc[1];

  float p[16], q[16];
#pragma unroll
  for (int u = 0; u < 16; ++u) {
    p[u] = __expf(a_lo - af[u]);
    q[u] = __expf(af[u] - a_hi);
  }

  const float Lf = (float)(NNODE * NNODE);
  float kt = 0.5f * (float)topk[0];

  float E0 = 1.f, E1 = 1.f, E0p = 1.f, E1p = 1.f;
  for (int it = 0; it < 6; ++it) {
    E0p = E0; E1p = E1;
    float r0 = 0.f, r1 = 0.f;
#pragma unroll
    for (int u = 0; u < 16; ++u) {
      float denom = fmaf(p[u], E0, q[u] * E1);
      float rin = __builtin_amdgcn_rcpf(denom);
      r0 = fmaf(p[u], rin, r0);
      r1 = fmaf(q[u], rin, r1);
    }
    for (int off = 32; off; off >>= 1) {
      r0 += __shfl_down(r0, off);
      r1 += __shfl_down(r1, off);
    }
    if (lane == 0) { rA[wave] = r0; rB[wave] = r1; }
    __syncthreads();
    if (t < 16) {
      r0 = rA[t]; r1 = rB[t];
      for (int off = 8; off; off >>= 1) {
        r0 += __shfl_down(r0, off);
        r1 += __shfl_down(r1, off);
      }
      if (t == 0) { bc[0] = (Lf - kt) / r0; bc[1] = kt / r1; }
    }
    __syncthreads();
    E0 = bc[0]; E1 = bc[1];
    __syncthreads();
  }

  // -------- final prob write (2 rows x 2 float4, coalesced per 16-lane group)
#pragma unroll
  for (int r = 0; r < 2; ++r) {
    float* xrow = Sout + (size_t)(rw + r * 64) * NNODE;
#pragma unroll
    for (int qd = 0; qd < 2; ++qd) {
      float o[4];
#pragma unroll
      for (int j = 0; j < 4; ++j) {
        int u = r * 8 + qd * 4 + j;
        float denom = fmaf(p[u], E0p, q[u] * E1p);
        o[j] = q[u] * E1 * __builtin_amdgcn_rcpf(denom);
      }
      *reinterpret_cast<float4*>(&xrow[jq4 + qd * 64]) = make_float4(o[0], o[1], o[2], o[3]);
    }
  }
}

// ---------------------------------------------------------------- scoring MLP
__global__ __launch_bounds__(256) void k_mlp(const float* __restrict__ gfs,
                                             const float* __restrict__ W1,
                                             const float* __restrict__ b1,
                                             const float* __restrict__ W2,
                                             const float* __restrict__ b2,
                                             float* __restrict__ ged) {
  __shared__ float sm[1024];
  int b = blockIdx.x, t = threadIdx.x;
  const float* s = gfs + b * 1024;
#pragma unroll
  for (int qq = 0; qq < 4; ++qq) sm[t + 256 * qq] = s[t + 256 * qq];
  __syncthreads();
  int j4 = (t & 15) * 4, kp = t >> 4;
  float4 acc = make_float4(0.f, 0.f, 0.f, 0.f);
#pragma unroll 8
  for (int k = 0; k < 64; ++k) {
    float4 w = *reinterpret_cast<const float4*>(&W1[(size_t)(kp * 64 + k) * 64 + j4]);
    float sv = sm[kp * 64 + k];
    acc.x += sv * w.x; acc.y += sv * w.y; acc.z += sv * w.z; acc.w += sv * w.w;
  }
  __syncthreads();
  *reinterpret_cast<float4*>(&sm[kp * 64 + j4]) = acc;
  __syncthreads();
  if (t < 64) {
    float h = b1[t];
#pragma unroll
    for (int kp2 = 0; kp2 < 16; ++kp2) h += sm[kp2 * 64 + t];
    h = fmaxf(h, 0.f);
    float v = h * W2[t];
    for (int off = 32; off; off >>= 1) v += __shfl_down(v, off);
    if (t == 0) ged[b] = 1.f / (1.f + __expf(-(v + b2[0])));
  }
}

// ================================================================ launch
extern "C" void kernel_launch(void* const* d_in, const int* in_sizes, int n_in,
                              void* d_out, int out_size, void* d_ws, size_t ws_size,
                              hipStream_t stream) {
  (void)in_sizes; (void)n_in; (void)out_size; (void)ws_size;
  const float* x1    = (const float*)d_in[0];
  const int*   cent1 = (const int*)  d_in[1];
  const float* rw1   = (const float*)d_in[2];
  const int*   src1  = (const int*)  d_in[3];
  const int*   dst1  = (const int*)  d_in[4];
  const float* x2    = (const float*)d_in[5];
  const int*   cent2 = (const int*)  d_in[6];
  const float* rw2   = (const float*)d_in[7];
  const int*   src2  = (const int*)  d_in[8];
  const int*   dst2  = (const int*)  d_in[9];
  const float* demb  = (const float*)d_in[10];
  const float* initW = (const float*)d_in[11];
  const float* initb = (const float*)d_in[12];
  const float* W1    = (const float*)d_in[13];
  const float* b1    = (const float*)d_in[14];
  const float* W2    = (const float*)d_in[15];
  const float* b2    = (const float*)d_in[16];
  const float* W3    = (const float*)d_in[17];
  const float* b3    = (const float*)d_in[18];
  const float* Aaff  = (const float*)d_in[19];
  const float* scW1  = (const float*)d_in[20];
  const float* scb1  = (const float*)d_in[21];
  const float* scW2  = (const float*)d_in[22];
  const float* scb2  = (const float*)d_in[23];
  const int*   topk  = (const int*)  d_in[24];

  float* ws    = (float*)d_ws;
  float* feat1 = ws;
  float* feat2 = ws + (size_t)1 * NTF;
  float* f13   = ws + (size_t)2 * NTF;
  float* f23   = ws + (size_t)3 * NTF;
  float* gfs   = ws + (size_t)4 * NTF;

  float* ged = (float*)d_out;
  float* S1  = ged + BATCH;
  float* S2  = S1 + (size_t)BATCH * NNODE * NNODE;

  // bucket-CSR scratch lives in the S1/S2 output regions (k_sim writes them
  // only AFTER k_chain has consumed the CSR). Per side: cnt (NT) + csr
  // (NT*DSLOT) = 8.5 MB < 16.78 MB region.
  int* cnt1 = (int*)S1;
  int* csr1 = cnt1 + NT;
  int* cnt2 = (int*)S2;
  int* csr2 = cnt2 + NT;

  const int gE = NEDGE / 256;

  // CSR: 1 dispatch + 2 DMA memsets (no count pass, no scan)
  hipMemsetAsync(cnt1, 0, NT * sizeof(int), stream);
  hipMemsetAsync(cnt2, 0, NT * sizeof(int), stream);
  k_fill<<<2 * gE, 256, 0, stream>>>(src1, dst1, cnt1, csr1, src2, dst2, cnt2, csr2);

  // fused conv chains (both sides), writes feat1/feat2/f13/f23/gfs
  k_chain<<<512, 256, 0, stream>>>(
      x1, cent1, rw1, x2, cent2, rw2, demb, initW, initb,
      W1, b1, W2, b2, W3, b3,
      cnt1, csr1, cnt2, csr2,
      feat1, feat2, f13, f23, gfs);

  // ged (only needs gfs; fills the gap right after chain)
  k_mlp<<<BATCH, 256, 0, stream>>>(gfs, scW1, scb1, scW2, scb2, ged);

  // both sims in one grid-512 launch
  k_sim<<<512, 1024, 0, stream>>>(feat1, feat2, f13, f23, Aaff, topk, S1, S2);
}

// Round 11
// 390.636 us; speedup vs baseline: 1.8159x; 1.0016x over previous
//
#include <hip/hip_runtime.h>
#include <math.h>

#define BATCH 256
#define NNODE 128
#define NT    32768      // BATCH*NNODE
#define FDIM  128
#define NEDGE 262144
#define LBL   29
#define MAXDEG 16
#define RWD   16
#define NTF   (NT * FDIM)
#define DSLOT 64         // per-node CSR bucket (in-degree ~ Poisson(8); P(>64) ~ e^-60)

// ---------------------------------------------------------------- CSR build: direct bucket fill
// No degree-count pass, no scan: each node owns a DSLOT-int slot; fill
// appends via atomicAdd on cnt. Degree = cnt (consumed by k_chain for dinv).
// Verified R10: replacing count+scan passes saved 22.6 us.
__global__ void k_fill(const int* __restrict__ src1, const int* __restrict__ dst1,
                       int* __restrict__ cnt1, int* __restrict__ csr1,
                       const int* __restrict__ src2, const int* __restrict__ dst2,
                       int* __restrict__ cnt2, int* __restrict__ csr2) {
  int e = blockIdx.x * 256 + threadIdx.x;
  if (e < NEDGE) {
    int node = dst1[e];
    int pos = atomicAdd(&cnt1[node], 1);
    csr1[(size_t)node * DSLOT + pos] = src1[e];
  } else if (e < 2 * NEDGE) {
    e -= NEDGE;
    int node = dst2[e];
    int pos = atomicAdd(&cnt2[node], 1);
    csr2[(size_t)node * DSLOT + pos] = src2[e];
  }
}

// ---------------------------------------------------------------- fused per-graph chain
// One block = one (graph, side). 256 threads, ~78 KB LDS -> 2 blocks/CU.
// Compute structure = EXACT verified version (172.6-179.5 us, VGPR 108).
// FROZEN: (a) R3 W-prefetch -> +24% FETCH, +4.4 us; (b) R6 global-W
// streaming -> register spill, 466 us. mm keeps W in LDS. Bucket CSR (R10)
// raised FETCH 8.8->12.3 MB but time unchanged. UNTOUCHED this round.
__global__ __launch_bounds__(256, 2) void k_chain(
    const float* __restrict__ x1, const int* __restrict__ cent1, const float* __restrict__ rw1,
    const float* __restrict__ x2, const int* __restrict__ cent2, const float* __restrict__ rw2,
    const float* __restrict__ demb,
    const float* __restrict__ initW, const float* __restrict__ initb,
    const float* __restrict__ W1, const float* __restrict__ b1,
    const float* __restrict__ W2, const float* __restrict__ b2,
    const float* __restrict__ W3, const float* __restrict__ b3,
    const int* __restrict__ cnt1, const int* __restrict__ csr1,
    const int* __restrict__ cnt2, const int* __restrict__ csr2,
    float* __restrict__ feat1G, float* __restrict__ feat2G,
    float* __restrict__ f13G, float* __restrict__ f23G,
    float* __restrict__ gfs) {
  __shared__ float X[128 * 132];      // 67584 B: concat / feat / h (phase-shared)
  __shared__ float WcB[16 * 132];     // 8448 B: W chunk (16 k-rows) / pool tmp [8*128]
  __shared__ float dvL[128];
  __shared__ float bL[128];
  __shared__ int   cnL[128];

  const int t = threadIdx.x;
  const int side = blockIdx.x >> 8;
  const int g = blockIdx.x & 255;
  const int nb = g * NNODE;

  const float* xg    = side ? x2 : x1;
  const int*   centg = side ? cent2 : cent1;
  const float* rwg   = side ? rw2 : rw1;
  const int*   cntg  = side ? cnt2 : cnt1;
  const int*   csrg  = side ? csr2 : csr1;
  float* featG = side ? feat2G : feat1G;
  float* f3G   = side ? f23G : f13G;

  // -------- phase -1: stage degree->dinv / concat features into X
  if (t < 128) {
    int dg = cntg[nb + t];
    dvL[t] = rsqrtf((float)(dg + 1));   // +1 self loop
    cnL[t] = dg;
  }
  {
    int d = t >> 1, sub = t & 1;          // 2 threads per node, 34 cols each
    int node = nb + d;
    int ct = centg[node];
    const float* xr = xg + (size_t)node * LBL;
    const float* er = demb + ct * MAXDEG;
    const float* rr = rwg + (size_t)node * RWD;
    for (int c = sub * 34; c < sub * 34 + 34; ++c) {
      float v = 0.f;
      if (c < LBL) v = xr[c];
      else if (c < LBL + MAXDEG) v = er[c - LBL];
      else if (c < 61) v = rr[c - 45];
      X[d * 68 + c] = v;                  // concat overlay, stride 68
    }
  }
  __syncthreads();

  const int rg = t >> 3;           // row base; thread rows rg + 32*r
  const int jq = (t & 7) * 4;      // col quads jq + 32*q

  // -------- phase 0: feat = relu(concat @ initW + initb); write featG; pool 0
  {
    float acc[4][16] = {};
    for (int kc = 0; kc < 64; kc += 16) {
      __syncthreads();
#pragma unroll
      for (int u = 0; u < 2; ++u) {
        int ll = t + 256 * u;                  // 0..511
        int row = ll >> 5, c4 = (ll & 31) * 4;
        int gk = kc + row;
        float4 w = (gk < 61) ? *reinterpret_cast<const float4*>(&initW[(size_t)gk * FDIM + c4])
                             : make_float4(0.f, 0.f, 0.f, 0.f);
        *reinterpret_cast<float4*>(&WcB[row * 132 + c4]) = w;
      }
      if (kc == 0 && t < 128) bL[t] = initb[t];
      __syncthreads();
      for (int kk = 0; kk < 16; kk += 4) {
        float av[4][4];
#pragma unroll
        for (int r = 0; r < 4; ++r) {
          float4 tmp = *reinterpret_cast<const float4*>(&X[(rg + 32 * r) * 68 + kc + kk]);
          av[r][0] = tmp.x; av[r][1] = tmp.y; av[r][2] = tmp.z; av[r][3] = tmp.w;
        }
#pragma unroll
        for (int c = 0; c < 4; ++c) {
          float4 w0 = *reinterpret_cast<const float4*>(&WcB[(kk + c) * 132 + jq]);
          float4 w1 = *reinterpret_cast<const float4*>(&WcB[(kk + c) * 132 + 32 + jq]);
          float4 w2 = *reinterpret_cast<const float4*>(&WcB[(kk + c) * 132 + 64 + jq]);
          float4 w3 = *reinterpret_cast<const float4*>(&WcB[(kk + c) * 132 + 96 + jq]);
#pragma unroll
          for (int r = 0; r < 4; ++r) {
            float a = av[r][c];
            acc[r][0]  += a * w0.x; acc[r][1]  += a * w0.y; acc[r][2]  += a * w0.z; acc[r][3]  += a * w0.w;
            acc[r][4]  += a * w1.x; acc[r][5]  += a * w1.y; acc[r][6]  += a * w1.z; acc[r][7]  += a * w1.w;
            acc[r][8]  += a * w2.x; acc[r][9]  += a * w2.y; acc[r][10] += a * w2.z; acc[r][11] += a * w2.w;
            acc[r][12] += a * w3.x; acc[r][13] += a * w3.y; acc[r][14] += a * w3.z; acc[r][15] += a * w3.w;
          }
        }
      }
    }
    __syncthreads();   // all concat reads done -> safe to overwrite X
#pragma unroll
    for (int r = 0; r < 4; ++r) {
      int row = rg + 32 * r;
#pragma unroll
      for (int q = 0; q < 4; ++q) {
        int col = q * 32 + jq;
        float4 bl = *reinterpret_cast<const float4*>(&bL[col]);
        float4 o = make_float4(fmaxf(acc[r][q * 4 + 0] + bl.x, 0.f),
                               fmaxf(acc[r][q * 4 + 1] + bl.y, 0.f),
                               fmaxf(acc[r][q * 4 + 2] + bl.z, 0.f),
                               fmaxf(acc[r][q * 4 + 3] + bl.w, 0.f));
        *reinterpret_cast<float4*>(&X[row * 132 + col]) = o;
        *reinterpret_cast<float4*>(&featG[(size_t)(nb + row) * FDIM + col]) = o;
      }
    }
    __syncthreads();
  }

  // -------- pool helper (256 threads: 8 row-groups x 16 rows)
#define POOL_LAYER(layer)                                                            \
  {                                                                                  \
    int j4 = (t & 31) * 4, qq = t >> 5;                                              \
    float4 pv = side ? make_float4(-INFINITY, -INFINITY, -INFINITY, -INFINITY)       \
                     : make_float4(0.f, 0.f, 0.f, 0.f);                              \
    for (int r = 0; r < 16; ++r) {                                                   \
      float4 fv = *reinterpret_cast<const float4*>(&X[(qq * 16 + r) * 132 + j4]);    \
      if (side) { pv.x = fmaxf(pv.x, fv.x); pv.y = fmaxf(pv.y, fv.y);                \
                  pv.z = fmaxf(pv.z, fv.z); pv.w = fmaxf(pv.w, fv.w); }              \
      else      { pv.x += fv.x; pv.y += fv.y; pv.z += fv.z; pv.w += fv.w; }          \
    }                                                                                \
    *reinterpret_cast<float4*>(&WcB[qq * 128 + j4]) = pv;                            \
    __syncthreads();                                                                 \
    if (t < 128) {                                                                   \
      float v = side ? -INFINITY : 0.f;                                              \
      for (int q2 = 0; q2 < 8; ++q2) {                                               \
        float w2 = WcB[q2 * 128 + t];                                                \
        v = side ? fmaxf(v, w2) : (v + w2);                                          \
      }                                                                              \
      gfs[g * 1024 + side * 512 + (layer) * 128 + t] = v;                            \
    }                                                                                \
  }

  POOL_LAYER(0)

  // -------- 3 conv layers
  for (int l = 0; l < 3; ++l) {
    const float* Wg = (l == 0) ? W1 : (l == 1) ? W2 : W3;   // SGPR select
    const float* bg = (l == 0) ? b1 : (l == 1) ? b2 : b3;
    // mm: h = (l>0 ? relu(X) : X) @ W_l   (acc in regs)
    float acc[4][16] = {};
    for (int kc = 0; kc < 128; kc += 16) {
      __syncthreads();   // protects WcB (pool tmp / prev chunk)
#pragma unroll
      for (int u = 0; u < 2; ++u) {
        int ll = t + 256 * u;
        int row = ll >> 5, c4 = (ll & 31) * 4;
        *reinterpret_cast<float4*>(&WcB[row * 132 + c4]) =
            *reinterpret_cast<const float4*>(&Wg[(size_t)(kc + row) * FDIM + c4]);
      }
      if (kc == 0 && t < 128) bL[t] = bg[t];
      __syncthreads();
      for (int kk = 0; kk < 16; kk += 4) {
        float av[4][4];
#pragma unroll
        for (int r = 0; r < 4; ++r) {
          float4 tmp = *reinterpret_cast<const float4*>(&X[(rg + 32 * r) * 132 + kc + kk]);
          if (l > 0) {
            tmp.x = fmaxf(tmp.x, 0.f); tmp.y = fmaxf(tmp.y, 0.f);
            tmp.z = fmaxf(tmp.z, 0.f); tmp.w = fmaxf(tmp.w, 0.f);
          }
          av[r][0] = tmp.x; av[r][1] = tmp.y; av[r][2] = tmp.z; av[r][3] = tmp.w;
        }
#pragma unroll
        for (int c = 0; c < 4; ++c) {
          float4 w0 = *reinterpret_cast<const float4*>(&WcB[(kk + c) * 132 + jq]);
          float4 w1 = *reinterpret_cast<const float4*>(&WcB[(kk + c) * 132 + 32 + jq]);
          float4 w2 = *reinterpret_cast<const float4*>(&WcB[(kk + c) * 132 + 64 + jq]);
          float4 w3 = *reinterpret_cast<const float4*>(&WcB[(kk + c) * 132 + 96 + jq]);
#pragma unroll
          for (int r = 0; r < 4; ++r) {
            float a = av[r][c];
            acc[r][0]  += a * w0.x; acc[r][1]  += a * w0.y; acc[r][2]  += a * w0.z; acc[r][3]  += a * w0.w;
            acc[r][4]  += a * w1.x; acc[r][5]  += a * w1.y; acc[r][6]  += a * w1.z; acc[r][7]  += a * w1.w;
            acc[r][8]  += a * w2.x; acc[r][9]  += a * w2.y; acc[r][10] += a * w2.z; acc[r][11] += a * w2.w;
            acc[r][12] += a * w3.x; acc[r][13] += a * w3.y; acc[r][14] += a * w3.z; acc[r][15] += a * w3.w;
          }
        }
      }
    }
    __syncthreads();   // all reads of X(feat) done -> overwrite with h
#pragma unroll
    for (int r = 0; r < 4; ++r) {
      int row = rg + 32 * r;
#pragma unroll
      for (int q = 0; q < 4; ++q) {
        int col = q * 32 + jq;
        *reinterpret_cast<float4*>(&X[row * 132 + col]) =
            make_float4(acc[r][q * 4 + 0], acc[r][q * 4 + 1],
                        acc[r][q * 4 + 2], acc[r][q * 4 + 3]);
      }
    }
    __syncthreads();   // h complete

    // gather into regs: feat[d][f] = b[f] + dd*(dd*h[d][f] + sum_s dinv[s]*h[s][f])
    {
      int d = t >> 1, fc = (t & 1) * 64;   // 2 threads/node, 64 cols each
      float dd = dvL[d];
      float4 a[16];
#pragma unroll
      for (int u = 0; u < 16; ++u) {
        float4 hv = *reinterpret_cast<const float4*>(&X[d * 132 + fc + u * 4]);
        a[u] = make_float4(dd * hv.x, dd * hv.y, dd * hv.z, dd * hv.w);
      }
      const int* elist = csrg + (size_t)(nb + d) * DSLOT;
      int cntd = cnL[d];
      // prefetch-by-1 from L2-resident bucket CSR
      int sj = (cntd > 0) ? (elist[0] - nb) : 0;
      for (int j = 0; j < cntd; ++j) {
        int sn = (j + 1 < cntd) ? (elist[j + 1] - nb) : 0;
        float w = dvL[sj];
#pragma unroll
        for (int u = 0; u < 16; ++u) {
          float4 hv = *reinterpret_cast<const float4*>(&X[sj * 132 + fc + u * 4]);
          a[u].x += w * hv.x; a[u].y += w * hv.y; a[u].z += w * hv.z; a[u].w += w * hv.w;
        }
        sj = sn;
      }
      __syncthreads();   // all h reads done -> overwrite X with feat
#pragma unroll
      for (int u = 0; u < 16; ++u) {
        float4 bl = *reinterpret_cast<const float4*>(&bL[fc + u * 4]);
        float4 o = make_float4(bl.x + dd * a[u].x, bl.y + dd * a[u].y,
                               bl.z + dd * a[u].z, bl.w + dd * a[u].w);
        *reinterpret_cast<float4*>(&X[d * 132 + fc + u * 4]) = o;
        if (l == 2)
          *reinterpret_cast<float4*>(&f3G[(size_t)(nb + d) * FDIM + fc + u * 4]) = o;
      }
    }
    __syncthreads();   // feat complete

    POOL_LAYER(l + 1)
  }
#undef POOL_LAYER
}

// ---------------------------------------------------------------- fused sim: S = (F1@A)@F2^T -> sinkhorn
// One block = one (sim, graph); grid 512. Barrier-free matmul phases (R5);
// 2x8 thread tile (R8). THIS ROUND: #pragma unroll 2 on both k0-loops --
// the loops are barrier-free straight-line code, so unrolling lets the
// compiler batch the Y-phase's 16-lane-broadcast global F1 loads (64 B/
// wave-inst, ~200cy L2 latency) and deepen LDS-read ILP. Unlike R3/R6
// failures, no live ranges cross barriers; __launch_bounds__(1024) caps
// VGPR at 128. FMA order per acc element unchanged -> bit-exact.
__global__ __launch_bounds__(1024) void k_sim(const float* __restrict__ F1s1,
                                              const float* __restrict__ F2s1,
                                              const float* __restrict__ F1s2,
                                              const float* __restrict__ F2s2,
                                              const float* __restrict__ Aaff,
                                              const int* __restrict__ topk,
                                              float* __restrict__ S1,
                                              float* __restrict__ S2) {
  __shared__ float X1[128 * 132];   // Aaff -> Y (LDS-overwrite trick)
  __shared__ float X2[128 * 132];   // F2^T (k-major)
  __shared__ float rA[16], rB[16], bc[2];

  const int t = threadIdx.x;
  const int half = blockIdx.x >> 8;
  const int b = blockIdx.x & 255;
  const float* F1b = (half ? F1s2 : F1s1) + (size_t)b * NNODE * FDIM;
  const float* F2b = (half ? F2s2 : F2s1) + (size_t)b * NNODE * FDIM;
  float* Sout = (half ? S2 : S1) + (size_t)b * NNODE * NNODE;

  // -------- stage Aaff row-major into X1 (coalesced, conflict-free)
#pragma unroll
  for (int p = 0; p < 4; ++p) {
    int fi = t + 1024 * p;            // float4 index 0..4095
    int row = fi >> 5, c4 = (fi & 31) * 4;
    *reinterpret_cast<float4*>(&X1[row * 132 + c4]) =
        *reinterpret_cast<const float4*>(&Aaff[(size_t)row * FDIM + c4]);
  }
  // -------- stage F2 transposed into X2 (one-time scattered writes, ~4-way)
  {
    int row = t >> 3;                 // 0..127 (all rows covered per p)
    int cq  = (t & 7) * 4;
#pragma unroll
    for (int p = 0; p < 4; ++p) {
      int c4 = p * 32 + cq;
      float4 v = *reinterpret_cast<const float4*>(&F2b[(size_t)row * FDIM + c4]);
      X2[(c4 + 0) * 132 + row] = v.x;
      X2[(c4 + 1) * 132 + row] = v.y;
      X2[(c4 + 2) * 132 + row] = v.z;
      X2[(c4 + 3) * 132 + row] = v.w;
    }
  }
  __syncthreads();

  const int rw = t >> 4;            // row pair: rw and rw+64 (0..63)
  const int jq4 = (t & 15) * 4;     // col pair: jq4 and jq4+64
  const float* f1r0 = F1b + (size_t)rw * FDIM;
  const float* f1r1 = F1b + (size_t)(rw + 64) * FDIM;

  float acc[2][8] = {};

  // -------- Y = F1 @ A : av from global (L3), w from X1; no barriers
#pragma unroll 2
  for (int k0 = 0; k0 < 128; k0 += 4) {
    float4 a40 = *reinterpret_cast<const float4*>(&f1r0[k0]);
    float4 a41 = *reinterpret_cast<const float4*>(&f1r1[k0]);
    float av0[4] = {a40.x, a40.y, a40.z, a40.w};
    float av1[4] = {a41.x, a41.y, a41.z, a41.w};
#pragma unroll
    for (int c = 0; c < 4; ++c) {
      const float* wb = &X1[(k0 + c) * 132];
      float4 w0 = *reinterpret_cast<const float4*>(&wb[jq4]);
      float4 w1 = *reinterpret_cast<const float4*>(&wb[jq4 + 64]);
      float a0 = av0[c], a1 = av1[c];
      acc[0][0] += a0 * w0.x; acc[0][1] += a0 * w0.y; acc[0][2] += a0 * w0.z; acc[0][3] += a0 * w0.w;
      acc[0][4] += a0 * w1.x; acc[0][5] += a0 * w1.y; acc[0][6] += a0 * w1.z; acc[0][7] += a0 * w1.w;
      acc[1][0] += a1 * w0.x; acc[1][1] += a1 * w0.y; acc[1][2] += a1 * w0.z; acc[1][3] += a1 * w0.w;
      acc[1][4] += a1 * w1.x; acc[1][5] += a1 * w1.y; acc[1][6] += a1 * w1.z; acc[1][7] += a1 * w1.w;
    }
  }
  __syncthreads();                   // all A reads done -> overwrite X1 with Y
  *reinterpret_cast<float4*>(&X1[rw * 132 + jq4]) =
      make_float4(acc[0][0], acc[0][1], acc[0][2], acc[0][3]);
  *reinterpret_cast<float4*>(&X1[rw * 132 + jq4 + 64]) =
      make_float4(acc[0][4], acc[0][5], acc[0][6], acc[0][7]);
  *reinterpret_cast<float4*>(&X1[(rw + 64) * 132 + jq4]) =
      make_float4(acc[1][0], acc[1][1], acc[1][2], acc[1][3]);
  *reinterpret_cast<float4*>(&X1[(rw + 64) * 132 + jq4 + 64]) =
      make_float4(acc[1][4], acc[1][5], acc[1][6], acc[1][7]);

#pragma unroll
  for (int r = 0; r < 2; ++r)
#pragma unroll
    for (int j = 0; j < 8; ++j) acc[r][j] = 0.f;
  __syncthreads();                   // Y visible; S-phase barrier-free

  // -------- S = Y @ F2^T : both operands LDS-resident, no barriers
#pragma unroll 2
  for (int k0 = 0; k0 < 128; k0 += 4) {
    float4 a40 = *reinterpret_cast<const float4*>(&X1[rw * 132 + k0]);
    float4 a41 = *reinterpret_cast<const float4*>(&X1[(rw + 64) * 132 + k0]);
    float av0[4] = {a40.x, a40.y, a40.z, a40.w};
    float av1[4] = {a41.x, a41.y, a41.z, a41.w};
#pragma unroll
    for (int c = 0; c < 4; ++c) {
      const float* wb = &X2[(k0 + c) * 132];
      float4 w0 = *reinterpret_cast<const float4*>(&wb[jq4]);
      float4 w1 = *reinterpret_cast<const float4*>(&wb[jq4 + 64]);
      float a0 = av0[c], a1 = av1[c];
      acc[0][0] += a0 * w0.x; acc[0][1] += a0 * w0.y; acc[0][2] += a0 * w0.z; acc[0][3] += a0 * w0.w;
      acc[0][4] += a0 * w1.x; acc[0][5] += a0 * w1.y; acc[0][6] += a0 * w1.z; acc[0][7] += a0 * w1.w;
      acc[1][0] += a1 * w0.x; acc[1][1] += a1 * w0.y; acc[1][2] += a1 * w0.z; acc[1][3] += a1 * w0.w;
      acc[1][4] += a1 * w1.x; acc[1][5] += a1 * w1.y; acc[1][6] += a1 * w1.z; acc[1][7] += a1 * w1.w;
    }
  }

  // -------- sinkhorn on register-resident S (ownership-agnostic reductions)
  const float* af = &acc[0][0];      // flat 16 values
  const int wave = t >> 6, lane = t & 63;
  {
    float mn = af[0], mx = af[0];
#pragma unroll
    for (int u = 1; u < 16; ++u) { mn = fminf(mn, af[u]); mx = fmaxf(mx, af[u]); }
    for (int off = 32; off; off >>= 1) {
      mn = fminf(mn, __shfl_down(mn, off));
      mx = fmaxf(mx, __shfl_down(mx, off));
    }
    if (lane == 0) { rA[wave] = mn; rB[wave] = mx; }
    __syncthreads();
    if (t < 16) {
      mn = rA[t]; mx = rB[t];
      for (int off = 8; off; off >>= 1) {
        mn = fminf(mn, __shfl_down(mn, off));
        mx = fmaxf(mx, __shfl_down(mx, off));
      }
      if (t == 0) { bc[0] = mn - 1.f; bc[1] = mx + 1.f; }
    }
    __syncthreads();
  }
  float a_lo = bc[0], a_hi = bc[1];

  float p[16], q[16];
#pragma unroll
  for (int u = 0; u < 16; ++u) {
    p[u] = __expf(a_lo - af[u]);
    q[u] = __expf(af[u] - a_hi);
  }

  const float Lf = (float)(NNODE * NNODE);
  float kt = 0.5f * (float)topk[0];

  float E0 = 1.f, E1 = 1.f, E0p = 1.f, E1p = 1.f;
  for (int it = 0; it < 6; ++it) {
    E0p = E0; E1p = E1;
    float r0 = 0.f, r1 = 0.f;
#pragma unroll
    for (int u = 0; u < 16; ++u) {
      float denom = fmaf(p[u], E0, q[u] * E1);
      float rin = __builtin_amdgcn_rcpf(denom);
      r0 = fmaf(p[u], rin, r0);
      r1 = fmaf(q[u], rin, r1);
    }
    for (int off = 32; off; off >>= 1) {
      r0 += __shfl_down(r0, off);
      r1 += __shfl_down(r1, off);
    }
    if (lane == 0) { rA[wave] = r0; rB[wave] = r1; }
    __syncthreads();
    if (t < 16) {
      r0 = rA[t]; r1 = rB[t];
      for (int off = 8; off; off >>= 1) {
        r0 += __shfl_down(r0, off);
        r1 += __shfl_down(r1, off);
      }
      if (t == 0) { bc[0] = (Lf - kt) / r0; bc[1] = kt / r1; }
    }
    __syncthreads();
    E0 = bc[0]; E1 = bc[1];
    __syncthreads();
  }

  // -------- final prob write (2 rows x 2 float4, coalesced per 16-lane group)
#pragma unroll
  for (int r = 0; r < 2; ++r) {
    float* xrow = Sout + (size_t)(rw + r * 64) * NNODE;
#pragma unroll
    for (int qd = 0; qd < 2; ++qd) {
      float o[4];
#pragma unroll
      for (int j = 0; j < 4; ++j) {
        int u = r * 8 + qd * 4 + j;
        float denom = fmaf(p[u], E0p, q[u] * E1p);
        o[j] = q[u] * E1 * __builtin_amdgcn_rcpf(denom);
      }
      *reinterpret_cast<float4*>(&xrow[jq4 + qd * 64]) = make_float4(o[0], o[1], o[2], o[3]);
    }
  }
}

// ---------------------------------------------------------------- scoring MLP
__global__ __launch_bounds__(256) void k_mlp(const float* __restrict__ gfs,
                                             const float* __restrict__ W1,
                                             const float* __restrict__ b1,
                                             const float* __restrict__ W2,
                                             const float* __restrict__ b2,
                                             float* __restrict__ ged) {
  __shared__ float sm[1024];
  int b = blockIdx.x, t = threadIdx.x;
  const float* s = gfs + b * 1024;
#pragma unroll
  for (int qq = 0; qq < 4; ++qq) sm[t + 256 * qq] = s[t + 256 * qq];
  __syncthreads();
  int j4 = (t & 15) * 4, kp = t >> 4;
  float4 acc = make_float4(0.f, 0.f, 0.f, 0.f);
#pragma unroll 8
  for (int k = 0; k < 64; ++k) {
    float4 w = *reinterpret_cast<const float4*>(&W1[(size_t)(kp * 64 + k) * 64 + j4]);
    float sv = sm[kp * 64 + k];
    acc.x += sv * w.x; acc.y += sv * w.y; acc.z += sv * w.z; acc.w += sv * w.w;
  }
  __syncthreads();
  *reinterpret_cast<float4*>(&sm[kp * 64 + j4]) = acc;
  __syncthreads();
  if (t < 64) {
    float h = b1[t];
#pragma unroll
    for (int kp2 = 0; kp2 < 16; ++kp2) h += sm[kp2 * 64 + t];
    h = fmaxf(h, 0.f);
    float v = h * W2[t];
    for (int off = 32; off; off >>= 1) v += __shfl_down(v, off);
    if (t == 0) ged[b] = 1.f / (1.f + __expf(-(v + b2[0])));
  }
}

// ================================================================ launch
extern "C" void kernel_launch(void* const* d_in, const int* in_sizes, int n_in,
                              void* d_out, int out_size, void* d_ws, size_t ws_size,
                              hipStream_t stream) {
  (void)in_sizes; (void)n_in; (void)out_size; (void)ws_size;
  const float* x1    = (const float*)d_in[0];
  const int*   cent1 = (const int*)  d_in[1];
  const float* rw1   = (const float*)d_in[2];
  const int*   src1  = (const int*)  d_in[3];
  const int*   dst1  = (const int*)  d_in[4];
  const float* x2    = (const float*)d_in[5];
  const int*   cent2 = (const int*)  d_in[6];
  const float* rw2   = (const float*)d_in[7];
  const int*   src2  = (const int*)  d_in[8];
  const int*   dst2  = (const int*)  d_in[9];
  const float* demb  = (const float*)d_in[10];
  const float* initW = (const float*)d_in[11];
  const float* initb = (const float*)d_in[12];
  const float* W1    = (const float*)d_in[13];
  const float* b1    = (const float*)d_in[14];
  const float* W2    = (const float*)d_in[15];
  const float* b2    = (const float*)d_in[16];
  const float* W3    = (const float*)d_in[17];
  const float* b3    = (const float*)d_in[18];
  const float* Aaff  = (const float*)d_in[19];
  const float* scW1  = (const float*)d_in[20];
  const float* scb1  = (const float*)d_in[21];
  const float* scW2  = (const float*)d_in[22];
  const float* scb2  = (const float*)d_in[23];
  const int*   topk  = (const int*)  d_in[24];

  float* ws    = (float*)d_ws;
  float* feat1 = ws;
  float* feat2 = ws + (size_t)1 * NTF;
  float* f13   = ws + (size_t)2 * NTF;
  float* f23   = ws + (size_t)3 * NTF;
  float* gfs   = ws + (size_t)4 * NTF;

  float* ged = (float*)d_out;
  float* S1  = ged + BATCH;
  float* S2  = S1 + (size_t)BATCH * NNODE * NNODE;

  // bucket-CSR scratch lives in the S1/S2 output regions (k_sim writes them
  // only AFTER k_chain has consumed the CSR). Per side: cnt (NT) + csr
  // (NT*DSLOT) = 8.5 MB < 16.78 MB region.
  int* cnt1 = (int*)S1;
  int* csr1 = cnt1 + NT;
  int* cnt2 = (int*)S2;
  int* csr2 = cnt2 + NT;

  const int gE = NEDGE / 256;

  // CSR: 1 dispatch + 2 DMA memsets (no count pass, no scan)
  hipMemsetAsync(cnt1, 0, NT * sizeof(int), stream);
  hipMemsetAsync(cnt2, 0, NT * sizeof(int), stream);
  k_fill<<<2 * gE, 256, 0, stream>>>(src1, dst1, cnt1, csr1, src2, dst2, cnt2, csr2);

  // fused conv chains (both sides), writes feat1/feat2/f13/f23/gfs
  k_chain<<<512, 256, 0, stream>>>(
      x1, cent1, rw1, x2, cent2, rw2, demb, initW, initb,
      W1, b1, W2, b2, W3, b3,
      cnt1, csr1, cnt2, csr2,
      feat1, feat2, f13, f23, gfs);

  // ged (only needs gfs; fills the gap right after chain)
  k_mlp<<<BATCH, 256, 0, stream>>>(gfs, scW1, scb1, scW2, scb2, ged);

  // both sims in one grid-512 launch
  k_sim<<<512, 1024, 0, stream>>>(feat1, feat2, f13, f23, Aaff, topk, S1, S2);
}

// Round 12
// 381.387 us; speedup vs baseline: 1.8600x; 1.0243x over previous
//
#include <hip/hip_runtime.h>
#include <math.h>

#define BATCH 256
#define NNODE 128
#define NT    32768      // BATCH*NNODE
#define FDIM  128
#define NEDGE 262144
#define LBL   29
#define MAXDEG 16
#define RWD   16
#define NTF   (NT * FDIM)
#define DSLOT 64         // per-node CSR bucket (in-degree ~ Poisson(8); P(>64) ~ e^-60)

// ---------------------------------------------------------------- CSR build: direct bucket fill
// Verified R10: replacing count+scan passes saved 22.6 us.
__global__ void k_fill(const int* __restrict__ src1, const int* __restrict__ dst1,
                       int* __restrict__ cnt1, int* __restrict__ csr1,
                       const int* __restrict__ src2, const int* __restrict__ dst2,
                       int* __restrict__ cnt2, int* __restrict__ csr2) {
  int e = blockIdx.x * 256 + threadIdx.x;
  if (e < NEDGE) {
    int node = dst1[e];
    int pos = atomicAdd(&cnt1[node], 1);
    csr1[(size_t)node * DSLOT + pos] = src1[e];
  } else if (e < 2 * NEDGE) {
    e -= NEDGE;
    int node = dst2[e];
    int pos = atomicAdd(&cnt2[node], 1);
    csr2[(size_t)node * DSLOT + pos] = src2[e];
  }
}

// ---------------------------------------------------------------- fused per-graph chain
// One block = one (graph, side). 256 threads, ~78 KB LDS -> 2 blocks/CU.
// FROZEN: (a) R3 W-prefetch -> +24% FETCH; (b) R6 global-W streaming ->
// register spill. mm keeps W in LDS with short register lifetimes.
// THIS ROUND: conv mm retiled 4x16 -> 8x8 (rows r0+16i, cols c0/c0+64):
// per 4-k LDS reads drop 20 -> 16 b128 (-20% mm LDS issue traffic, the
// modeled bottleneck). Same FMA count, per-element k-order unchanged ->
// bit-exact. a-reads 16-lane broadcast (free); w-reads/h-writes 64
// contiguous dwords/wave (2-way, free). Phase 0 + gather untouched.
__global__ __launch_bounds__(256, 2) void k_chain(
    const float* __restrict__ x1, const int* __restrict__ cent1, const float* __restrict__ rw1,
    const float* __restrict__ x2, const int* __restrict__ cent2, const float* __restrict__ rw2,
    const float* __restrict__ demb,
    const float* __restrict__ initW, const float* __restrict__ initb,
    const float* __restrict__ W1, const float* __restrict__ b1,
    const float* __restrict__ W2, const float* __restrict__ b2,
    const float* __restrict__ W3, const float* __restrict__ b3,
    const int* __restrict__ cnt1, const int* __restrict__ csr1,
    const int* __restrict__ cnt2, const int* __restrict__ csr2,
    float* __restrict__ feat1G, float* __restrict__ feat2G,
    float* __restrict__ f13G, float* __restrict__ f23G,
    float* __restrict__ gfs) {
  __shared__ float X[128 * 132];      // 67584 B: concat / feat / h (phase-shared)
  __shared__ float WcB[16 * 132];     // 8448 B: W chunk (16 k-rows) / pool tmp [8*128]
  __shared__ float dvL[128];
  __shared__ float bL[128];
  __shared__ int   cnL[128];

  const int t = threadIdx.x;
  const int side = blockIdx.x >> 8;
  const int g = blockIdx.x & 255;
  const int nb = g * NNODE;

  const float* xg    = side ? x2 : x1;
  const int*   centg = side ? cent2 : cent1;
  const float* rwg   = side ? rw2 : rw1;
  const int*   cntg  = side ? cnt2 : cnt1;
  const int*   csrg  = side ? csr2 : csr1;
  float* featG = side ? feat2G : feat1G;
  float* f3G   = side ? f23G : f13G;

  // -------- phase -1: stage degree->dinv / concat features into X
  if (t < 128) {
    int dg = cntg[nb + t];
    dvL[t] = rsqrtf((float)(dg + 1));   // +1 self loop
    cnL[t] = dg;
  }
  {
    int d = t >> 1, sub = t & 1;          // 2 threads per node, 34 cols each
    int node = nb + d;
    int ct = centg[node];
    const float* xr = xg + (size_t)node * LBL;
    const float* er = demb + ct * MAXDEG;
    const float* rr = rwg + (size_t)node * RWD;
    for (int c = sub * 34; c < sub * 34 + 34; ++c) {
      float v = 0.f;
      if (c < LBL) v = xr[c];
      else if (c < LBL + MAXDEG) v = er[c - LBL];
      else if (c < 61) v = rr[c - 45];
      X[d * 68 + c] = v;                  // concat overlay, stride 68
    }
  }
  __syncthreads();

  const int rg = t >> 3;           // phase-0 row base; thread rows rg + 32*r
  const int jq = (t & 7) * 4;      // phase-0 col quads jq + 32*q

  // -------- phase 0: feat = relu(concat @ initW + initb); write featG; pool 0
  {
    float acc[4][16] = {};
    for (int kc = 0; kc < 64; kc += 16) {
      __syncthreads();
#pragma unroll
      for (int u = 0; u < 2; ++u) {
        int ll = t + 256 * u;                  // 0..511
        int row = ll >> 5, c4 = (ll & 31) * 4;
        int gk = kc + row;
        float4 w = (gk < 61) ? *reinterpret_cast<const float4*>(&initW[(size_t)gk * FDIM + c4])
                             : make_float4(0.f, 0.f, 0.f, 0.f);
        *reinterpret_cast<float4*>(&WcB[row * 132 + c4]) = w;
      }
      if (kc == 0 && t < 128) bL[t] = initb[t];
      __syncthreads();
      for (int kk = 0; kk < 16; kk += 4) {
        float av[4][4];
#pragma unroll
        for (int r = 0; r < 4; ++r) {
          float4 tmp = *reinterpret_cast<const float4*>(&X[(rg + 32 * r) * 68 + kc + kk]);
          av[r][0] = tmp.x; av[r][1] = tmp.y; av[r][2] = tmp.z; av[r][3] = tmp.w;
        }
#pragma unroll
        for (int c = 0; c < 4; ++c) {
          float4 w0 = *reinterpret_cast<const float4*>(&WcB[(kk + c) * 132 + jq]);
          float4 w1 = *reinterpret_cast<const float4*>(&WcB[(kk + c) * 132 + 32 + jq]);
          float4 w2 = *reinterpret_cast<const float4*>(&WcB[(kk + c) * 132 + 64 + jq]);
          float4 w3 = *reinterpret_cast<const float4*>(&WcB[(kk + c) * 132 + 96 + jq]);
#pragma unroll
          for (int r = 0; r < 4; ++r) {
            float a = av[r][c];
            acc[r][0]  += a * w0.x; acc[r][1]  += a * w0.y; acc[r][2]  += a * w0.z; acc[r][3]  += a * w0.w;
            acc[r][4]  += a * w1.x; acc[r][5]  += a * w1.y; acc[r][6]  += a * w1.z; acc[r][7]  += a * w1.w;
            acc[r][8]  += a * w2.x; acc[r][9]  += a * w2.y; acc[r][10] += a * w2.z; acc[r][11] += a * w2.w;
            acc[r][12] += a * w3.x; acc[r][13] += a * w3.y; acc[r][14] += a * w3.z; acc[r][15] += a * w3.w;
          }
        }
      }
    }
    __syncthreads();   // all concat reads done -> safe to overwrite X
#pragma unroll
    for (int r = 0; r < 4; ++r) {
      int row = rg + 32 * r;
#pragma unroll
      for (int q = 0; q < 4; ++q) {
        int col = q * 32 + jq;
        float4 bl = *reinterpret_cast<const float4*>(&bL[col]);
        float4 o = make_float4(fmaxf(acc[r][q * 4 + 0] + bl.x, 0.f),
                               fmaxf(acc[r][q * 4 + 1] + bl.y, 0.f),
                               fmaxf(acc[r][q * 4 + 2] + bl.z, 0.f),
                               fmaxf(acc[r][q * 4 + 3] + bl.w, 0.f));
        *reinterpret_cast<float4*>(&X[row * 132 + col]) = o;
        *reinterpret_cast<float4*>(&featG[(size_t)(nb + row) * FDIM + col]) = o;
      }
    }
    __syncthreads();
  }

  // -------- pool helper (256 threads: 8 row-groups x 16 rows)
#define POOL_LAYER(layer)                                                            \
  {                                                                                  \
    int j4 = (t & 31) * 4, qq = t >> 5;                                              \
    float4 pv = side ? make_float4(-INFINITY, -INFINITY, -INFINITY, -INFINITY)       \
                     : make_float4(0.f, 0.f, 0.f, 0.f);                              \
    for (int r = 0; r < 16; ++r) {                                                   \
      float4 fv = *reinterpret_cast<const float4*>(&X[(qq * 16 + r) * 132 + j4]);    \
      if (side) { pv.x = fmaxf(pv.x, fv.x); pv.y = fmaxf(pv.y, fv.y);                \
                  pv.z = fmaxf(pv.z, fv.z); pv.w = fmaxf(pv.w, fv.w); }              \
      else      { pv.x += fv.x; pv.y += fv.y; pv.z += fv.z; pv.w += fv.w; }          \
    }                                                                                \
    *reinterpret_cast<float4*>(&WcB[qq * 128 + j4]) = pv;                            \
    __syncthreads();                                                                 \
    if (t < 128) {                                                                   \
      float v = side ? -INFINITY : 0.f;                                              \
      for (int q2 = 0; q2 < 8; ++q2) {                                               \
        float w2 = WcB[q2 * 128 + t];                                                \
        v = side ? fmaxf(v, w2) : (v + w2);                                          \
      }                                                                              \
      gfs[g * 1024 + side * 512 + (layer) * 128 + t] = v;                            \
    }                                                                                \
  }

  POOL_LAYER(0)

  // -------- 3 conv layers (8x8 mm tile)
  const int r0 = t >> 4;           // rows r0 + 16*i, i<8
  const int c0 = (t & 15) * 4;     // cols c0 and c0+64
  for (int l = 0; l < 3; ++l) {
    const float* Wg = (l == 0) ? W1 : (l == 1) ? W2 : W3;   // SGPR select
    const float* bg = (l == 0) ? b1 : (l == 1) ? b2 : b3;
    // mm: h = (l>0 ? relu(X) : X) @ W_l   (acc in regs)
    float acc[8][8] = {};   // [i][j]: j<4 -> col c0+j ; j>=4 -> col c0+64+(j-4)
    for (int kc = 0; kc < 128; kc += 16) {
      __syncthreads();   // protects WcB (pool tmp / prev chunk)
#pragma unroll
      for (int u = 0; u < 2; ++u) {
        int ll = t + 256 * u;
        int row = ll >> 5, c4 = (ll & 31) * 4;
        *reinterpret_cast<float4*>(&WcB[row * 132 + c4]) =
            *reinterpret_cast<const float4*>(&Wg[(size_t)(kc + row) * FDIM + c4]);
      }
      if (kc == 0 && t < 128) bL[t] = bg[t];
      __syncthreads();
      for (int kk = 0; kk < 16; kk += 4) {
        float av[8][4];
#pragma unroll
        for (int i = 0; i < 8; ++i) {
          float4 tmp = *reinterpret_cast<const float4*>(&X[(r0 + 16 * i) * 132 + kc + kk]);
          if (l > 0) {
            tmp.x = fmaxf(tmp.x, 0.f); tmp.y = fmaxf(tmp.y, 0.f);
            tmp.z = fmaxf(tmp.z, 0.f); tmp.w = fmaxf(tmp.w, 0.f);
          }
          av[i][0] = tmp.x; av[i][1] = tmp.y; av[i][2] = tmp.z; av[i][3] = tmp.w;
        }
#pragma unroll
        for (int c = 0; c < 4; ++c) {
          float4 w0 = *reinterpret_cast<const float4*>(&WcB[(kk + c) * 132 + c0]);
          float4 w1 = *reinterpret_cast<const float4*>(&WcB[(kk + c) * 132 + c0 + 64]);
#pragma unroll
          for (int i = 0; i < 8; ++i) {
            float a = av[i][c];
            acc[i][0] += a * w0.x; acc[i][1] += a * w0.y; acc[i][2] += a * w0.z; acc[i][3] += a * w0.w;
            acc[i][4] += a * w1.x; acc[i][5] += a * w1.y; acc[i][6] += a * w1.z; acc[i][7] += a * w1.w;
          }
        }
      }
    }
    __syncthreads();   // all reads of X(feat) done -> overwrite with h
#pragma unroll
    for (int i = 0; i < 8; ++i) {
      int row = r0 + 16 * i;
      *reinterpret_cast<float4*>(&X[row * 132 + c0]) =
          make_float4(acc[i][0], acc[i][1], acc[i][2], acc[i][3]);
      *reinterpret_cast<float4*>(&X[row * 132 + c0 + 64]) =
          make_float4(acc[i][4], acc[i][5], acc[i][6], acc[i][7]);
    }
    __syncthreads();   // h complete

    // gather into regs: feat[d][f] = b[f] + dd*(dd*h[d][f] + sum_s dinv[s]*h[s][f])
    {
      int d = t >> 1, fc = (t & 1) * 64;   // 2 threads/node, 64 cols each
      float dd = dvL[d];
      float4 a[16];
#pragma unroll
      for (int u = 0; u < 16; ++u) {
        float4 hv = *reinterpret_cast<const float4*>(&X[d * 132 + fc + u * 4]);
        a[u] = make_float4(dd * hv.x, dd * hv.y, dd * hv.z, dd * hv.w);
      }
      const int* elist = csrg + (size_t)(nb + d) * DSLOT;
      int cntd = cnL[d];
      // prefetch-by-1 from L2-resident bucket CSR
      int sj = (cntd > 0) ? (elist[0] - nb) : 0;
      for (int j = 0; j < cntd; ++j) {
        int sn = (j + 1 < cntd) ? (elist[j + 1] - nb) : 0;
        float w = dvL[sj];
#pragma unroll
        for (int u = 0; u < 16; ++u) {
          float4 hv = *reinterpret_cast<const float4*>(&X[sj * 132 + fc + u * 4]);
          a[u].x += w * hv.x; a[u].y += w * hv.y; a[u].z += w * hv.z; a[u].w += w * hv.w;
        }
        sj = sn;
      }
      __syncthreads();   // all h reads done -> overwrite X with feat
#pragma unroll
      for (int u = 0; u < 16; ++u) {
        float4 bl = *reinterpret_cast<const float4*>(&bL[fc + u * 4]);
        float4 o = make_float4(bl.x + dd * a[u].x, bl.y + dd * a[u].y,
                               bl.z + dd * a[u].z, bl.w + dd * a[u].w);
        *reinterpret_cast<float4*>(&X[d * 132 + fc + u * 4]) = o;
        if (l == 2)
          *reinterpret_cast<float4*>(&f3G[(size_t)(nb + d) * FDIM + fc + u * 4]) = o;
      }
    }
    __syncthreads();   // feat complete

    POOL_LAYER(l + 1)
  }
#undef POOL_LAYER
}

// ---------------------------------------------------------------- fused sim: S = (F1@A)@F2^T -> sinkhorn
// One block = one (sim, graph); grid 512. Barrier-free matmul phases (R5);
// 2x8 thread tile (R8); unroll 2 (R11, neutral). Unchanged this round.
__global__ __launch_bounds__(1024) void k_sim(const float* __restrict__ F1s1,
                                              const float* __restrict__ F2s1,
                                              const float* __restrict__ F1s2,
                                              const float* __restrict__ F2s2,
                                              const float* __restrict__ Aaff,
                                              const int* __restrict__ topk,
                                              float* __restrict__ S1,
                                              float* __restrict__ S2) {
  __shared__ float X1[128 * 132];   // Aaff -> Y (LDS-overwrite trick)
  __shared__ float X2[128 * 132];   // F2^T (k-major)
  __shared__ float rA[16], rB[16], bc[2];

  const int t = threadIdx.x;
  const int half = blockIdx.x >> 8;
  const int b = blockIdx.x & 255;
  const float* F1b = (half ? F1s2 : F1s1) + (size_t)b * NNODE * FDIM;
  const float* F2b = (half ? F2s2 : F2s1) + (size_t)b * NNODE * FDIM;
  float* Sout = (half ? S2 : S1) + (size_t)b * NNODE * NNODE;

  // -------- stage Aaff row-major into X1 (coalesced, conflict-free)
#pragma unroll
  for (int p = 0; p < 4; ++p) {
    int fi = t + 1024 * p;            // float4 index 0..4095
    int row = fi >> 5, c4 = (fi & 31) * 4;
    *reinterpret_cast<float4*>(&X1[row * 132 + c4]) =
        *reinterpret_cast<const float4*>(&Aaff[(size_t)row * FDIM + c4]);
  }
  // -------- stage F2 transposed into X2 (one-time scattered writes, ~4-way)
  {
    int row = t >> 3;                 // 0..127 (all rows covered per p)
    int cq  = (t & 7) * 4;
#pragma unroll
    for (int p = 0; p < 4; ++p) {
      int c4 = p * 32 + cq;
      float4 v = *reinterpret_cast<const float4*>(&F2b[(size_t)row * FDIM + c4]);
      X2[(c4 + 0) * 132 + row] = v.x;
      X2[(c4 + 1) * 132 + row] = v.y;
      X2[(c4 + 2) * 132 + row] = v.z;
      X2[(c4 + 3) * 132 + row] = v.w;
    }
  }
  __syncthreads();

  const int rw = t >> 4;            // row pair: rw and rw+64 (0..63)
  const int jq4 = (t & 15) * 4;     // col pair: jq4 and jq4+64
  const float* f1r0 = F1b + (size_t)rw * FDIM;
  const float* f1r1 = F1b + (size_t)(rw + 64) * FDIM;

  float acc[2][8] = {};

  // -------- Y = F1 @ A : av from global (L3), w from X1; no barriers
#pragma unroll 2
  for (int k0 = 0; k0 < 128; k0 += 4) {
    float4 a40 = *reinterpret_cast<const float4*>(&f1r0[k0]);
    float4 a41 = *reinterpret_cast<const float4*>(&f1r1[k0]);
    float av0[4] = {a40.x, a40.y, a40.z, a40.w};
    float av1[4] = {a41.x, a41.y, a41.z, a41.w};
#pragma unroll
    for (int c = 0; c < 4; ++c) {
      const float* wb = &X1[(k0 + c) * 132];
      float4 w0 = *reinterpret_cast<const float4*>(&wb[jq4]);
      float4 w1 = *reinterpret_cast<const float4*>(&wb[jq4 + 64]);
      float a0 = av0[c], a1 = av1[c];
      acc[0][0] += a0 * w0.x; acc[0][1] += a0 * w0.y; acc[0][2] += a0 * w0.z; acc[0][3] += a0 * w0.w;
      acc[0][4] += a0 * w1.x; acc[0][5] += a0 * w1.y; acc[0][6] += a0 * w1.z; acc[0][7] += a0 * w1.w;
      acc[1][0] += a1 * w0.x; acc[1][1] += a1 * w0.y; acc[1][2] += a1 * w0.z; acc[1][3] += a1 * w0.w;
      acc[1][4] += a1 * w1.x; acc[1][5] += a1 * w1.y; acc[1][6] += a1 * w1.z; acc[1][7] += a1 * w1.w;
    }
  }
  __syncthreads();                   // all A reads done -> overwrite X1 with Y
  *reinterpret_cast<float4*>(&X1[rw * 132 + jq4]) =
      make_float4(acc[0][0], acc[0][1], acc[0][2], acc[0][3]);
  *reinterpret_cast<float4*>(&X1[rw * 132 + jq4 + 64]) =
      make_float4(acc[0][4], acc[0][5], acc[0][6], acc[0][7]);
  *reinterpret_cast<float4*>(&X1[(rw + 64) * 132 + jq4]) =
      make_float4(acc[1][0], acc[1][1], acc[1][2], acc[1][3]);
  *reinterpret_cast<float4*>(&X1[(rw + 64) * 132 + jq4 + 64]) =
      make_float4(acc[1][4], acc[1][5], acc[1][6], acc[1][7]);

#pragma unroll
  for (int r = 0; r < 2; ++r)
#pragma unroll
    for (int j = 0; j < 8; ++j) acc[r][j] = 0.f;
  __syncthreads();                   // Y visible; S-phase barrier-free

  // -------- S = Y @ F2^T : both operands LDS-resident, no barriers
#pragma unroll 2
  for (int k0 = 0; k0 < 128; k0 += 4) {
    float4 a40 = *reinterpret_cast<const float4*>(&X1[rw * 132 + k0]);
    float4 a41 = *reinterpret_cast<const float4*>(&X1[(rw + 64) * 132 + k0]);
    float av0[4] = {a40.x, a40.y, a40.z, a40.w};
    float av1[4] = {a41.x, a41.y, a41.z, a41.w};
#pragma unroll
    for (int c = 0; c < 4; ++c) {
      const float* wb = &X2[(k0 + c) * 132];
      float4 w0 = *reinterpret_cast<const float4*>(&wb[jq4]);
      float4 w1 = *reinterpret_cast<const float4*>(&wb[jq4 + 64]);
      float a0 = av0[c], a1 = av1[c];
      acc[0][0] += a0 * w0.x; acc[0][1] += a0 * w0.y; acc[0][2] += a0 * w0.z; acc[0][3] += a0 * w0.w;
      acc[0][4] += a0 * w1.x; acc[0][5] += a0 * w1.y; acc[0][6] += a0 * w1.z; acc[0][7] += a0 * w1.w;
      acc[1][0] += a1 * w0.x; acc[1][1] += a1 * w0.y; acc[1][2] += a1 * w0.z; acc[1][3] += a1 * w0.w;
      acc[1][4] += a1 * w1.x; acc[1][5] += a1 * w1.y; acc[1][6] += a1 * w1.z; acc[1][7] += a1 * w1.w;
    }
  }

  // -------- sinkhorn on register-resident S (ownership-agnostic reductions)
  const float* af = &acc[0][0];      // flat 16 values
  const int wave = t >> 6, lane = t & 63;
  {
    float mn = af[0], mx = af[0];
#pragma unroll
    for (int u = 1; u < 16; ++u) { mn = fminf(mn, af[u]); mx = fmaxf(mx, af[u]); }
    for (int off = 32; off; off >>= 1) {
      mn = fminf(mn, __shfl_down(mn, off));
      mx = fmaxf(mx, __shfl_down(mx, off));
    }
    if (lane == 0) { rA[wave] = mn; rB[wave] = mx; }
    __syncthreads();
    if (t < 16) {
      mn = rA[t]; mx = rB[t];
      for (int off = 8; off; off >>= 1) {
        mn = fminf(mn, __shfl_down(mn, off));
        mx = fmaxf(mx, __shfl_down(mx, off));
      }
      if (t == 0) { bc[0] = mn - 1.f; bc[1] = mx + 1.f; }
    }
    __syncthreads();
  }
  float a_lo = bc[0], a_hi = bc[1];

  float p[16], q[16];
#pragma unroll
  for (int u = 0; u < 16; ++u) {
    p[u] = __expf(a_lo - af[u]);
    q[u] = __expf(af[u] - a_hi);
  }

  const float Lf = (float)(NNODE * NNODE);
  float kt = 0.5f * (float)topk[0];

  float E0 = 1.f, E1 = 1.f, E0p = 1.f, E1p = 1.f;
  for (int it = 0; it < 6; ++it) {
    E0p = E0; E1p = E1;
    float r0 = 0.f, r1 = 0.f;
#pragma unroll
    for (int u = 0; u < 16; ++u) {
      float denom = fmaf(p[u], E0, q[u] * E1);
      float rin = __builtin_amdgcn_rcpf(denom);
      r0 = fmaf(p[u], rin, r0);
      r1 = fmaf(q[u], rin, r1);
    }
    for (int off = 32; off; off >>= 1) {
      r0 += __shfl_down(r0, off);
      r1 += __shfl_down(r1, off);
    }
    if (lane == 0) { rA[wave] = r0; rB[wave] = r1; }
    __syncthreads();
    if (t < 16) {
      r0 = rA[t]; r1 = rB[t];
      for (int off = 8; off; off >>= 1) {
        r0 += __shfl_down(r0, off);
        r1 += __shfl_down(r1, off);
      }
      if (t == 0) { bc[0] = (Lf - kt) / r0; bc[1] = kt / r1; }
    }
    __syncthreads();
    E0 = bc[0]; E1 = bc[1];
    __syncthreads();
  }

  // -------- final prob write (2 rows x 2 float4, coalesced per 16-lane group)
#pragma unroll
  for (int r = 0; r < 2; ++r) {
    float* xrow = Sout + (size_t)(rw + r * 64) * NNODE;
#pragma unroll
    for (int qd = 0; qd < 2; ++qd) {
      float o[4];
#pragma unroll
      for (int j = 0; j < 4; ++j) {
        int u = r * 8 + qd * 4 + j;
        float denom = fmaf(p[u], E0p, q[u] * E1p);
        o[j] = q[u] * E1 * __builtin_amdgcn_rcpf(denom);
      }
      *reinterpret_cast<float4*>(&xrow[jq4 + qd * 64]) = make_float4(o[0], o[1], o[2], o[3]);
    }
  }
}

// ---------------------------------------------------------------- scoring MLP
__global__ __launch_bounds__(256) void k_mlp(const float* __restrict__ gfs,
                                             const float* __restrict__ W1,
                                             const float* __restrict__ b1,
                                             const float* __restrict__ W2,
                                             const float* __restrict__ b2,
                                             float* __restrict__ ged) {
  __shared__ float sm[1024];
  int b = blockIdx.x, t = threadIdx.x;
  const float* s = gfs + b * 1024;
#pragma unroll
  for (int qq = 0; qq < 4; ++qq) sm[t + 256 * qq] = s[t + 256 * qq];
  __syncthreads();
  int j4 = (t & 15) * 4, kp = t >> 4;
  float4 acc = make_float4(0.f, 0.f, 0.f, 0.f);
#pragma unroll 8
  for (int k = 0; k < 64; ++k) {
    float4 w = *reinterpret_cast<const float4*>(&W1[(size_t)(kp * 64 + k) * 64 + j4]);
    float sv = sm[kp * 64 + k];
    acc.x += sv * w.x; acc.y += sv * w.y; acc.z += sv * w.z; acc.w += sv * w.w;
  }
  __syncthreads();
  *reinterpret_cast<float4*>(&sm[kp * 64 + j4]) = acc;
  __syncthreads();
  if (t < 64) {
    float h = b1[t];
#pragma unroll
    for (int kp2 = 0; kp2 < 16; ++kp2) h += sm[kp2 * 64 + t];
    h = fmaxf(h, 0.f);
    float v = h * W2[t];
    for (int off = 32; off; off >>= 1) v += __shfl_down(v, off);
    if (t == 0) ged[b] = 1.f / (1.f + __expf(-(v + b2[0])));
  }
}

// ================================================================ launch
extern "C" void kernel_launch(void* const* d_in, const int* in_sizes, int n_in,
                              void* d_out, int out_size, void* d_ws, size_t ws_size,
                              hipStream_t stream) {
  (void)in_sizes; (void)n_in; (void)out_size; (void)ws_size;
  const float* x1    = (const float*)d_in[0];
  const int*   cent1 = (const int*)  d_in[1];
  const float* rw1   = (const float*)d_in[2];
  const int*   src1  = (const int*)  d_in[3];
  const int*   dst1  = (const int*)  d_in[4];
  const float* x2    = (const float*)d_in[5];
  const int*   cent2 = (const int*)  d_in[6];
  const float* rw2   = (const float*)d_in[7];
  const int*   src2  = (const int*)  d_in[8];
  const int*   dst2  = (const int*)  d_in[9];
  const float* demb  = (const float*)d_in[10];
  const float* initW = (const float*)d_in[11];
  const float* initb = (const float*)d_in[12];
  const float* W1    = (const float*)d_in[13];
  const float* b1    = (const float*)d_in[14];
  const float* W2    = (const float*)d_in[15];
  const float* b2    = (const float*)d_in[16];
  const float* W3    = (const float*)d_in[17];
  const float* b3    = (const float*)d_in[18];
  const float* Aaff  = (const float*)d_in[19];
  const float* scW1  = (const float*)d_in[20];
  const float* scb1  = (const float*)d_in[21];
  const float* scW2  = (const float*)d_in[22];
  const float* scb2  = (const float*)d_in[23];
  const int*   topk  = (const int*)  d_in[24];

  float* ws    = (float*)d_ws;
  float* feat1 = ws;
  float* feat2 = ws + (size_t)1 * NTF;
  float* f13   = ws + (size_t)2 * NTF;
  float* f23   = ws + (size_t)3 * NTF;
  float* gfs   = ws + (size_t)4 * NTF;

  float* ged = (float*)d_out;
  float* S1  = ged + BATCH;
  float* S2  = S1 + (size_t)BATCH * NNODE * NNODE;

  // bucket-CSR scratch lives in the S1/S2 output regions (k_sim writes them
  // only AFTER k_chain has consumed the CSR). Per side: cnt (NT) + csr
  // (NT*DSLOT) = 8.5 MB < 16.78 MB region.
  int* cnt1 = (int*)S1;
  int* csr1 = cnt1 + NT;
  int* cnt2 = (int*)S2;
  int* csr2 = cnt2 + NT;

  const int gE = NEDGE / 256;

  // CSR: 1 dispatch + 2 DMA memsets (no count pass, no scan)
  hipMemsetAsync(cnt1, 0, NT * sizeof(int), stream);
  hipMemsetAsync(cnt2, 0, NT * sizeof(int), stream);
  k_fill<<<2 * gE, 256, 0, stream>>>(src1, dst1, cnt1, csr1, src2, dst2, cnt2, csr2);

  // fused conv chains (both sides), writes feat1/feat2/f13/f23/gfs
  k_chain<<<512, 256, 0, stream>>>(
      x1, cent1, rw1, x2, cent2, rw2, demb, initW, initb,
      W1, b1, W2, b2, W3, b3,
      cnt1, csr1, cnt2, csr2,
      feat1, feat2, f13, f23, gfs);

  // ged (only needs gfs; fills the gap right after chain)
  k_mlp<<<BATCH, 256, 0, stream>>>(gfs, scW1, scb1, scW2, scb2, ged);

  // both sims in one grid-512 launch
  k_sim<<<512, 1024, 0, stream>>>(feat1, feat2, f13, f23, Aaff, topk, S1, S2);
}